// Round 1
// baseline (980.378 us; speedup 1.0000x reference)
//
#include <hip/hip_runtime.h>

// Problem constants (setup_inputs: B=2, C=256, H=W=48, p=3)
constexpr int B_  = 2;
constexpr int C_  = 256;
constexpr int H_  = 48;
constexpr int W_  = 48;
constexpr int N_  = H_ * W_;          // 2304
constexpr int PH_ = H_ + 2;           // 50
constexpr int PW_ = W_ + 2;           // 50
constexpr int NP_ = PH_ * PW_;        // 2500
constexpr int CC_ = C_ * C_;          // 65536
constexpr int NCH_ = 18;              // n-chunks for score partial argmax
constexpr int NC_  = N_ / NCH_;       // 128
constexpr int NSIT_ = 12;             // Newton-Schulz iterations

// ---------------- reduction helpers ----------------
__device__ inline float waveRed(float v) {
  #pragma unroll
  for (int o = 32; o > 0; o >>= 1) v += __shfl_down(v, o);
  return v;
}

// ---------------- kernels ----------------

// Compute per-(b,c) mean over N and write centered rows. which=0: content->fc, 1: style->fs
__global__ __launch_bounds__(256) void center_kernel(
    const float* __restrict__ content, const float* __restrict__ style,
    float* __restrict__ fc, float* __restrict__ fs, float* __restrict__ mean_s) {
  int t = blockIdx.x;                 // 0 .. 2*B*C-1
  int which = t / (B_ * C_);
  int bc = t % (B_ * C_);
  const float* src = which ? style : content;
  float* dst = which ? fs : fc;
  const float* row = src + (size_t)bc * N_;
  float acc = 0.f;
  for (int i = threadIdx.x; i < N_; i += 256) acc += row[i];
  __shared__ float sm[4];
  float r = waveRed(acc);
  if ((threadIdx.x & 63) == 0) sm[threadIdx.x >> 6] = r;
  __syncthreads();
  float mean = (sm[0] + sm[1] + sm[2] + sm[3]) * (1.0f / N_);
  for (int i = threadIdx.x; i < N_; i += 256) dst[(size_t)bc * N_ + i] = row[i] - mean;
  if (which == 1 && threadIdx.x == 0) mean_s[bc] = mean;
}

// Batched covariance: m=0,1 content batches; m=2,3 style batches. A4[m] = f f^T /(N-1)
__global__ __launch_bounds__(256) void cov_kernel(
    const float* __restrict__ fc, const float* __restrict__ fs, float* __restrict__ A4) {
  int m = blockIdx.z;
  const float* f = (m < 2) ? (fc + (size_t)m * C_ * N_) : (fs + (size_t)(m - 2) * C_ * N_);
  int i0 = blockIdx.y * 32, j0 = blockIdx.x * 32;
  int tx = threadIdx.x & 15, ty = threadIdx.x >> 4;
  __shared__ float sI[32][33], sJ[32][33];
  float acc[2][2] = {};
  for (int x0 = 0; x0 < N_; x0 += 32) {
    for (int l = threadIdx.x; l < 1024; l += 256) {
      int r = l >> 5, c = l & 31;
      sI[r][c] = f[(size_t)(i0 + r) * N_ + x0 + c];
      sJ[r][c] = f[(size_t)(j0 + r) * N_ + x0 + c];
    }
    __syncthreads();
    #pragma unroll
    for (int k = 0; k < 32; k++) {
      float a0 = sI[ty * 2][k], a1 = sI[ty * 2 + 1][k];
      float b0 = sJ[tx * 2][k], b1 = sJ[tx * 2 + 1][k];
      acc[0][0] += a0 * b0; acc[0][1] += a0 * b1;
      acc[1][0] += a1 * b0; acc[1][1] += a1 * b1;
    }
    __syncthreads();
  }
  float sc = 1.0f / (float)(N_ - 1);
  for (int a = 0; a < 2; a++)
    for (int b = 0; b < 2; b++)
      A4[(size_t)m * CC_ + (size_t)(i0 + ty * 2 + a) * C_ + (j0 + tx * 2 + b)] = acc[a][b] * sc;
}

// Trace-normalize: Ya = A/s, Za = I, scal[m]=s
__global__ __launch_bounds__(256) void ns_init(
    const float* __restrict__ A4, float* __restrict__ Ya, float* __restrict__ Za,
    float* __restrict__ scal) {
  int m = blockIdx.x;
  const float* A = A4 + (size_t)m * CC_;
  float d = A[(size_t)threadIdx.x * 257];   // diag element
  __shared__ float sm[4];
  float r = waveRed(d);
  if ((threadIdx.x & 63) == 0) sm[threadIdx.x >> 6] = r;
  __syncthreads();
  float trace = sm[0] + sm[1] + sm[2] + sm[3];
  float s = 1.1f * trace / (float)C_;
  if (threadIdx.x == 0) scal[m] = s;
  float inv = 1.0f / s;
  for (int i = threadIdx.x; i < CC_; i += 256) {
    Ya[(size_t)m * CC_ + i] = A[i] * inv;
    Za[(size_t)m * CC_ + i] = ((i >> 8) == (i & 255)) ? 1.0f : 0.0f;
  }
}

// T = 3I - Z*Y  (batched 4)
__global__ __launch_bounds__(256) void ns_stepA(
    const float* __restrict__ Z, const float* __restrict__ Y, float* __restrict__ T) {
  int m = blockIdx.z;
  const float* A = Z + (size_t)m * CC_;
  const float* Bm = Y + (size_t)m * CC_;
  float* out = T + (size_t)m * CC_;
  int i0 = blockIdx.y * 32, j0 = blockIdx.x * 32;
  int tx = threadIdx.x & 15, ty = threadIdx.x >> 4;
  __shared__ float sA[32][33], sB[32][33];
  float acc[2][2] = {};
  for (int k0 = 0; k0 < 256; k0 += 32) {
    for (int l = threadIdx.x; l < 1024; l += 256) {
      int r = l >> 5, c = l & 31;
      sA[r][c] = A[(size_t)(i0 + r) * 256 + k0 + c];
      sB[r][c] = Bm[(size_t)(k0 + r) * 256 + j0 + c];
    }
    __syncthreads();
    #pragma unroll
    for (int kk = 0; kk < 32; kk++) {
      float a0 = sA[ty * 2][kk], a1 = sA[ty * 2 + 1][kk];
      float b0 = sB[kk][tx * 2], b1 = sB[kk][tx * 2 + 1];
      acc[0][0] += a0 * b0; acc[0][1] += a0 * b1;
      acc[1][0] += a1 * b0; acc[1][1] += a1 * b1;
    }
    __syncthreads();
  }
  for (int a = 0; a < 2; a++)
    for (int b = 0; b < 2; b++) {
      int i = i0 + ty * 2 + a, j = j0 + tx * 2 + b;
      out[(size_t)i * 256 + j] = ((i == j) ? 3.0f : 0.0f) - acc[a][b];
    }
}

// z<4: Yn = 0.5*Y*T ; z>=4: Zn = 0.5*T*Z  (batched)
__global__ __launch_bounds__(256) void ns_stepB(
    const float* __restrict__ Y, const float* __restrict__ Z, const float* __restrict__ T,
    float* __restrict__ Yn, float* __restrict__ Zn) {
  int zz = blockIdx.z;
  int m = zz & 3;
  bool doY = (zz < 4);
  const float* A = doY ? (Y + (size_t)m * CC_) : (T + (size_t)m * CC_);
  const float* Bm = doY ? (T + (size_t)m * CC_) : (Z + (size_t)m * CC_);
  float* out = doY ? (Yn + (size_t)m * CC_) : (Zn + (size_t)m * CC_);
  int i0 = blockIdx.y * 32, j0 = blockIdx.x * 32;
  int tx = threadIdx.x & 15, ty = threadIdx.x >> 4;
  __shared__ float sA[32][33], sB[32][33];
  float acc[2][2] = {};
  for (int k0 = 0; k0 < 256; k0 += 32) {
    for (int l = threadIdx.x; l < 1024; l += 256) {
      int r = l >> 5, c = l & 31;
      sA[r][c] = A[(size_t)(i0 + r) * 256 + k0 + c];
      sB[r][c] = Bm[(size_t)(k0 + r) * 256 + j0 + c];
    }
    __syncthreads();
    #pragma unroll
    for (int kk = 0; kk < 32; kk++) {
      float a0 = sA[ty * 2][kk], a1 = sA[ty * 2 + 1][kk];
      float b0 = sB[kk][tx * 2], b1 = sB[kk][tx * 2 + 1];
      acc[0][0] += a0 * b0; acc[0][1] += a0 * b1;
      acc[1][0] += a1 * b0; acc[1][1] += a1 * b1;
    }
    __syncthreads();
  }
  for (int a = 0; a < 2; a++)
    for (int b = 0; b < 2; b++) {
      int i = i0 + ty * 2 + a, j = j0 + tx * 2 + b;
      out[(size_t)i * 256 + j] = 0.5f * acc[a][b];
    }
}

// Apply whitening (Z/sqrt(s)) * f, write into zero-initialized padded buffers.
// m=0,1: content -> ncP [b][c][NP] ; m=2,3: style -> nsP [b][NP][c]
__global__ __launch_bounds__(256) void whiten_pad(
    const float* __restrict__ Zf, const float* __restrict__ scal,
    const float* __restrict__ fc, const float* __restrict__ fs,
    float* __restrict__ ncP, float* __restrict__ nsP) {
  int m = blockIdx.z;
  const float* Wm = Zf + (size_t)m * CC_;
  const float* f = (m < 2) ? (fc + (size_t)m * C_ * N_) : (fs + (size_t)(m - 2) * C_ * N_);
  int c0 = blockIdx.y * 32, x0 = blockIdx.x * 32;
  int tx = threadIdx.x & 15, ty = threadIdx.x >> 4;
  __shared__ float sA[32][33], sB[32][33];
  float acc[2][2] = {};
  for (int k0 = 0; k0 < 256; k0 += 32) {
    for (int l = threadIdx.x; l < 1024; l += 256) {
      int r = l >> 5, c = l & 31;
      sA[r][c] = Wm[(size_t)(c0 + r) * 256 + k0 + c];
      sB[r][c] = f[(size_t)(k0 + r) * N_ + x0 + c];
    }
    __syncthreads();
    #pragma unroll
    for (int kk = 0; kk < 32; kk++) {
      float a0 = sA[ty * 2][kk], a1 = sA[ty * 2 + 1][kk];
      float b0 = sB[kk][tx * 2], b1 = sB[kk][tx * 2 + 1];
      acc[0][0] += a0 * b0; acc[0][1] += a0 * b1;
      acc[1][0] += a1 * b0; acc[1][1] += a1 * b1;
    }
    __syncthreads();
  }
  float rs = rsqrtf(scal[m]);
  int b = (m < 2) ? m : (m - 2);
  for (int a = 0; a < 2; a++)
    for (int bb = 0; bb < 2; bb++) {
      int c = c0 + ty * 2 + a, x = x0 + tx * 2 + bb;
      int h = x / W_, w = x % W_;
      int pp = (h + 1) * PW_ + (w + 1);
      float val = acc[a][bb] * rs;
      if (m < 2) ncP[((size_t)b * C_ + c) * NP_ + pp] = val;
      else       nsP[((size_t)b * NP_ + pp) * C_ + c] = val;
    }
}

// q[b][p] = sum_c nsP[b][p][c]^2  (one wave per padded position)
__global__ __launch_bounds__(256) void q_kernel(const float* __restrict__ nsP, float* __restrict__ q) {
  int wid = (blockIdx.x * 256 + threadIdx.x) >> 6;
  int lane = threadIdx.x & 63;
  if (wid >= B_ * NP_) return;
  const float* v = nsP + (size_t)wid * C_;
  float acc = 0.f;
  #pragma unroll
  for (int c = lane; c < C_; c += 64) { float t = v[c]; acc += t * t; }
  acc = waveRed(acc);
  if (lane == 0) q[wid] = acc;
}

// kninv[b][n] = rsqrt( sum over 3x3 of q )
__global__ __launch_bounds__(256) void kninv_kernel(const float* __restrict__ q, float* __restrict__ kninv) {
  int t = blockIdx.x * 256 + threadIdx.x;
  if (t >= B_ * N_) return;
  int b = t / N_, n = t % N_;
  int hn = n / W_, wn = n % W_;
  const float* qb = q + (size_t)b * NP_ + hn * PW_ + wn;
  float s = 0.f;
  #pragma unroll
  for (int i = 0; i < 3; i++)
    #pragma unroll
    for (int j = 0; j < 3; j++) s += qb[i * PW_ + j];
  kninv[t] = rsqrtf(s);
}

// M = nsP[b] (2500x256) * ncP[b] (256x2500) -> M (2500x2500)
__global__ __launch_bounds__(256) void m_kernel(
    const float* __restrict__ Asty, const float* __restrict__ Bcon, float* __restrict__ M) {
  int i0 = blockIdx.y * 64, j0 = blockIdx.x * 64;
  int tx = threadIdx.x & 15, ty = threadIdx.x >> 4;
  __shared__ float sA[64][17], sB[16][65];
  float acc[4][4] = {};
  for (int k0 = 0; k0 < 256; k0 += 16) {
    for (int l = threadIdx.x; l < 1024; l += 256) {
      int r = l >> 4, kk = l & 15;
      int row = i0 + r;
      sA[r][kk] = (row < NP_) ? Asty[(size_t)row * C_ + k0 + kk] : 0.f;
    }
    for (int l = threadIdx.x; l < 1024; l += 256) {
      int kk = l >> 6, c = l & 63;
      int col = j0 + c;
      sB[kk][c] = (col < NP_) ? Bcon[(size_t)(k0 + kk) * NP_ + col] : 0.f;
    }
    __syncthreads();
    #pragma unroll
    for (int kk = 0; kk < 16; kk++) {
      float a[4], bb[4];
      #pragma unroll
      for (int u = 0; u < 4; u++) a[u] = sA[ty * 4 + u][kk];
      #pragma unroll
      for (int u = 0; u < 4; u++) bb[u] = sB[kk][tx * 4 + u];
      #pragma unroll
      for (int u = 0; u < 4; u++)
        #pragma unroll
        for (int v = 0; v < 4; v++) acc[u][v] += a[u] * bb[v];
    }
    __syncthreads();
  }
  for (int u = 0; u < 4; u++)
    for (int v = 0; v < 4; v++) {
      int i = i0 + ty * 4 + u, j = j0 + tx * 4 + v;
      if (i < NP_ && j < NP_) M[(size_t)i * NP_ + j] = acc[u][v];
    }
}

// Partial argmax over an n-chunk for each content position m.
__global__ __launch_bounds__(256) void score_kernel(
    const float* __restrict__ M, const float* __restrict__ kninv,
    float* __restrict__ pval, int* __restrict__ pidx, int b) {
  int m = blockIdx.x * 256 + threadIdx.x;     // 0..N-1
  int h = m / W_, w = m % W_;
  int cm = h * PW_ + w;
  int n0 = blockIdx.y * NC_;
  const float* kni = kninv + (size_t)b * N_;
  float best = -3.4e38f;
  int bidx = n0;
  for (int n = n0; n < n0 + NC_; n++) {
    int hn = n / W_, wn = n % W_;
    int rn = hn * PW_ + wn;
    const float* base = M + (size_t)rn * NP_ + cm;
    float s = 0.f;
    #pragma unroll
    for (int i = 0; i < 3; i++)
      #pragma unroll
      for (int j = 0; j < 3; j++) s += base[(size_t)(i * PW_ + j) * (NP_ + 1)];
    s *= kni[n];
    if (s > best) { best = s; bidx = n; }
  }
  pval[((size_t)b * NCH_ + blockIdx.y) * N_ + m] = best;
  pidx[((size_t)b * NCH_ + blockIdx.y) * N_ + m] = bidx;
}

// Final argmax across chunks (ascending => first-max wins, matches jnp.argmax)
__global__ __launch_bounds__(256) void argmax_final(
    const float* __restrict__ pval, const int* __restrict__ pidx, int* __restrict__ idxb) {
  int t = blockIdx.x * 256 + threadIdx.x;
  if (t >= B_ * N_) return;
  int b = t / N_, m = t % N_;
  float best = -3.4e38f; int bidx = 0;
  for (int ch = 0; ch < NCH_; ch++) {
    float v = pval[((size_t)b * NCH_ + ch) * N_ + m];
    int i = pidx[((size_t)b * NCH_ + ch) * N_ + m];
    if (v > best) { best = v; bidx = i; }
  }
  idxb[t] = bidx;
}

// Overlap-add reassembly: recon[b][m][c] layout (position-major)
__global__ __launch_bounds__(256) void reassemble_kernel(
    const float* __restrict__ nsP, const int* __restrict__ idxb, float* __restrict__ recon) {
  int bm = blockIdx.x;
  int b = bm / N_, m = bm % N_;
  int h = m / W_, w = m % W_;
  int c = threadIdx.x;
  float acc = 0.f; int cnt = 0;
  for (int di = 0; di < 3; di++) {
    int hs = h + 1 - di; if (hs < 0 || hs >= H_) continue;
    for (int dj = 0; dj < 3; dj++) {
      int ws = w + 1 - dj; if (ws < 0 || ws >= W_) continue;
      int n = idxb[(size_t)b * N_ + hs * W_ + ws];
      int hn = n / W_, wn = n % W_;
      int pp = (hn + di) * PW_ + (wn + dj);
      acc += nsP[((size_t)b * NP_ + pp) * C_ + c];
      cnt++;
    }
  }
  recon[((size_t)b * N_ + m) * C_ + c] = acc / (float)cnt;
}

// Partial column sums of recon over x-chunks
__global__ __launch_bounds__(256) void rmean_part(const float* __restrict__ recon, float* __restrict__ pmr) {
  int b = blockIdx.y, ch = blockIdx.x, c = threadIdx.x;
  float acc = 0.f;
  int x0 = ch * (N_ / 16);
  for (int x = x0; x < x0 + (N_ / 16); x++) acc += recon[((size_t)b * N_ + x) * C_ + c];
  pmr[((size_t)b * 16 + ch) * C_ + c] = acc;
}

__global__ __launch_bounds__(256) void rmean_fin(const float* __restrict__ pmr, float* __restrict__ mr) {
  int b = blockIdx.x, c = threadIdx.x;
  float acc = 0.f;
  for (int ch = 0; ch < 16; ch++) acc += pmr[((size_t)b * 16 + ch) * C_ + c];
  mr[(size_t)b * C_ + c] = acc * (1.0f / N_);
}

// stylized = sqrt(cov_s)*(recon-mr) + mean_s ; out = (1-ss)*content + ss*stylized
__global__ __launch_bounds__(256) void color_blend(
    const float* __restrict__ Yf, const float* __restrict__ scal,
    const float* __restrict__ recon, const float* __restrict__ mr,
    const float* __restrict__ msty, const float* __restrict__ content,
    const float* __restrict__ ssp, float* __restrict__ out) {
  int b = blockIdx.z;
  const float* Wm = Yf + (size_t)(2 + b) * CC_;
  int c0 = blockIdx.y * 32, x0 = blockIdx.x * 32;
  int tx = threadIdx.x & 15, ty = threadIdx.x >> 4;
  __shared__ float sA[32][33], sB[32][33];
  float acc[2][2] = {};
  for (int k0 = 0; k0 < 256; k0 += 32) {
    for (int l = threadIdx.x; l < 1024; l += 256) {
      int r = l >> 5, c = l & 31;
      sA[r][c] = Wm[(size_t)(c0 + r) * 256 + k0 + c];
    }
    for (int l = threadIdx.x; l < 1024; l += 256) {
      int dd = l & 31, xx = l >> 5;
      sB[dd][xx] = recon[((size_t)b * N_ + x0 + xx) * C_ + k0 + dd] - mr[(size_t)b * C_ + k0 + dd];
    }
    __syncthreads();
    #pragma unroll
    for (int kk = 0; kk < 32; kk++) {
      float a0 = sA[ty * 2][kk], a1 = sA[ty * 2 + 1][kk];
      float b0 = sB[kk][tx * 2], b1 = sB[kk][tx * 2 + 1];
      acc[0][0] += a0 * b0; acc[0][1] += a0 * b1;
      acc[1][0] += a1 * b0; acc[1][1] += a1 * b1;
    }
    __syncthreads();
  }
  float sq = sqrtf(scal[2 + b]);
  float ss = ssp[0];
  for (int u = 0; u < 2; u++)
    for (int v = 0; v < 2; v++) {
      int c = c0 + ty * 2 + u, x = x0 + tx * 2 + v;
      float sty = acc[u][v] * sq + msty[(size_t)b * C_ + c];
      size_t o = ((size_t)b * C_ + c) * N_ + x;
      out[o] = (1.0f - ss) * content[o] + ss * sty;
    }
}

// ---------------- host launch ----------------
extern "C" void kernel_launch(void* const* d_in, const int* in_sizes, int n_in,
                              void* d_out, int out_size, void* d_ws, size_t ws_size,
                              hipStream_t stream) {
  (void)in_sizes; (void)n_in; (void)out_size; (void)ws_size;
  const float* content = (const float*)d_in[0];
  const float* style   = (const float*)d_in[1];
  const float* ssp     = (const float*)d_in[2];   // style_strength scalar
  float* out = (float*)d_out;
  float* W = (float*)d_ws;

  // workspace layout (floats)
  size_t off = 0;
  float* fc   = W + off; off += (size_t)B_ * C_ * N_;
  float* fs   = W + off; off += (size_t)B_ * C_ * N_;
  float* nsP  = W + off; off += (size_t)B_ * NP_ * C_;
  float* ncP  = W + off; off += (size_t)B_ * C_ * NP_;
  float* A4   = W + off; off += (size_t)4 * CC_;
  float* Ya   = W + off; off += (size_t)4 * CC_;
  float* Yb   = W + off; off += (size_t)4 * CC_;
  float* Za   = W + off; off += (size_t)4 * CC_;
  float* Zb   = W + off; off += (size_t)4 * CC_;
  float* T4   = W + off; off += (size_t)4 * CC_;
  float* scal = W + off; off += 4;
  float* msty = W + off; off += (size_t)B_ * C_;
  float* mr   = W + off; off += (size_t)B_ * C_;
  float* pmr  = W + off; off += (size_t)B_ * 16 * C_;
  float* q    = W + off; off += (size_t)B_ * NP_;
  float* kni  = W + off; off += (size_t)B_ * N_;
  float* pval = W + off; off += (size_t)B_ * NCH_ * N_;
  float* Mb   = W + off; off += (size_t)NP_ * NP_;
  float* recon= W + off; off += (size_t)B_ * N_ * C_;
  int* pidx = (int*)(W + off); off += (size_t)B_ * NCH_ * N_;
  int* idxb = (int*)(W + off); off += (size_t)B_ * N_;

  // zero padded buffers (borders must stay 0)
  hipMemsetAsync(nsP, 0, (size_t)B_ * NP_ * C_ * sizeof(float), stream);
  hipMemsetAsync(ncP, 0, (size_t)B_ * C_ * NP_ * sizeof(float), stream);

  center_kernel<<<2 * B_ * C_, 256, 0, stream>>>(content, style, fc, fs, msty);
  cov_kernel<<<dim3(8, 8, 4), 256, 0, stream>>>(fc, fs, A4);
  ns_init<<<4, 256, 0, stream>>>(A4, Ya, Za, scal);

  float *Ycur = Ya, *Zcur = Za, *Yalt = Yb, *Zalt = Zb;
  for (int it = 0; it < NSIT_; it++) {
    ns_stepA<<<dim3(8, 8, 4), 256, 0, stream>>>(Zcur, Ycur, T4);
    ns_stepB<<<dim3(8, 8, 8), 256, 0, stream>>>(Ycur, Zcur, T4, Yalt, Zalt);
    float* t;
    t = Ycur; Ycur = Yalt; Yalt = t;
    t = Zcur; Zcur = Zalt; Zalt = t;
  }

  whiten_pad<<<dim3(N_ / 32, 8, 4), 256, 0, stream>>>(Zcur, scal, fc, fs, ncP, nsP);
  q_kernel<<<(B_ * NP_ + 3) / 4, 256, 0, stream>>>(nsP, q);
  kninv_kernel<<<(B_ * N_ + 255) / 256, 256, 0, stream>>>(q, kni);

  for (int b = 0; b < B_; b++) {
    m_kernel<<<dim3((NP_ + 63) / 64, (NP_ + 63) / 64), 256, 0, stream>>>(
        nsP + (size_t)b * NP_ * C_, ncP + (size_t)b * C_ * NP_, Mb);
    score_kernel<<<dim3(N_ / 256, NCH_), 256, 0, stream>>>(Mb, kni, pval, pidx, b);
  }
  argmax_final<<<(B_ * N_ + 255) / 256, 256, 0, stream>>>(pval, pidx, idxb);
  reassemble_kernel<<<B_ * N_, 256, 0, stream>>>(nsP, idxb, recon);
  rmean_part<<<dim3(16, B_), 256, 0, stream>>>(recon, pmr);
  rmean_fin<<<B_, 256, 0, stream>>>(pmr, mr);
  color_blend<<<dim3(N_ / 32, 8, B_), 256, 0, stream>>>(
      Ycur, scal, recon, mr, msty, content, ssp, out);
}

// Round 2
// 659.594 us; speedup vs baseline: 1.4863x; 1.4863x over previous
//
#include <hip/hip_runtime.h>

// Problem constants (setup_inputs: B=2, C=256, H=W=48, p=3)
constexpr int B_  = 2;
constexpr int C_  = 256;
constexpr int H_  = 48;
constexpr int W_  = 48;
constexpr int N_  = H_ * W_;          // 2304
constexpr int PH_ = H_ + 2;           // 50
constexpr int PW_ = W_ + 2;           // 50
constexpr int NP_ = PH_ * PW_;        // 2500
constexpr int CC_ = C_ * C_;          // 65536
constexpr int NCH_ = 18;              // n-chunks for score partial argmax
constexpr int NC_  = N_ / NCH_;       // 128
constexpr int NSIT_ = 8;              // Newton-Schulz iterations (e8 ~ 1e-15)
constexpr int KCH_ = 9;               // cov K-chunks (2304 = 9*256)

// ---------------- reduction helpers ----------------
__device__ inline float waveRed(float v) {
  #pragma unroll
  for (int o = 32; o > 0; o >>= 1) v += __shfl_down(v, o);
  return v;
}

// ---------------- kernels ----------------

// Compute per-(b,c) mean over N and write centered rows. which=0: content->fc, 1: style->fs
__global__ __launch_bounds__(256) void center_kernel(
    const float* __restrict__ content, const float* __restrict__ style,
    float* __restrict__ fc, float* __restrict__ fs, float* __restrict__ mean_s) {
  int t = blockIdx.x;                 // 0 .. 2*B*C-1
  int which = t / (B_ * C_);
  int bc = t % (B_ * C_);
  const float* src = which ? style : content;
  float* dst = which ? fs : fc;
  const float* row = src + (size_t)bc * N_;
  float acc = 0.f;
  for (int i = threadIdx.x; i < N_; i += 256) acc += row[i];
  __shared__ float sm[4];
  float r = waveRed(acc);
  if ((threadIdx.x & 63) == 0) sm[threadIdx.x >> 6] = r;
  __syncthreads();
  float mean = (sm[0] + sm[1] + sm[2] + sm[3]) * (1.0f / N_);
  for (int i = threadIdx.x; i < N_; i += 256) dst[(size_t)bc * N_ + i] = row[i] - mean;
  if (which == 1 && threadIdx.x == 0) mean_s[bc] = mean;
}

// K-split covariance partials: pcov[ci][m][i][j] = sum over x-chunk of f_i f_j
// z = ci*4 + m ; m=0,1 content batches, m=2,3 style batches.
__global__ __launch_bounds__(256) void cov_kernel(
    const float* __restrict__ fc, const float* __restrict__ fs, float* __restrict__ pcov) {
  int z = blockIdx.z;
  int m = z & 3, ci = z >> 2;
  const float* f = (m < 2) ? (fc + (size_t)m * C_ * N_) : (fs + (size_t)(m - 2) * C_ * N_);
  int i0 = blockIdx.y * 32, j0 = blockIdx.x * 32;
  int tx = threadIdx.x & 15, ty = threadIdx.x >> 4;
  __shared__ float sI[32][33], sJ[32][33];
  float acc[2][2] = {};
  int x0e = ci * 256 + 256;
  for (int x0 = ci * 256; x0 < x0e; x0 += 32) {
    for (int l = threadIdx.x; l < 1024; l += 256) {
      int r = l >> 5, c = l & 31;
      sI[r][c] = f[(size_t)(i0 + r) * N_ + x0 + c];
      sJ[r][c] = f[(size_t)(j0 + r) * N_ + x0 + c];
    }
    __syncthreads();
    #pragma unroll
    for (int k = 0; k < 32; k++) {
      float a0 = sI[ty * 2][k], a1 = sI[ty * 2 + 1][k];
      float b0 = sJ[tx * 2][k], b1 = sJ[tx * 2 + 1][k];
      acc[0][0] += a0 * b0; acc[0][1] += a0 * b1;
      acc[1][0] += a1 * b0; acc[1][1] += a1 * b1;
    }
    __syncthreads();
  }
  float* out = pcov + ((size_t)ci * 4 + m) * CC_;
  for (int a = 0; a < 2; a++)
    for (int b = 0; b < 2; b++)
      out[(size_t)(i0 + ty * 2 + a) * C_ + (j0 + tx * 2 + b)] = acc[a][b];
}

// A4[m] = (sum_ci pcov[ci][m]) / (N-1)
__global__ __launch_bounds__(256) void covreduce(
    const float* __restrict__ pcov, float* __restrict__ A4) {
  int t = blockIdx.x * 256 + threadIdx.x;   // over 4*CC
  float acc = 0.f;
  #pragma unroll
  for (int ci = 0; ci < KCH_; ci++) acc += pcov[(size_t)ci * 4 * CC_ + t];
  A4[t] = acc * (1.0f / (float)(N_ - 1));
}

// Trace-normalize into K-split partial sets: Yp[0]=A/s, Yp[1]=0, Zp[0]=I, Zp[1]=0.
// grid (16, 4): blockIdx.y = m, blockIdx.x = slice (CC/16 each)
__global__ __launch_bounds__(256) void ns_init(
    const float* __restrict__ A4, float* __restrict__ Yp, float* __restrict__ Zp,
    float* __restrict__ scal) {
  int m = blockIdx.y, s = blockIdx.x;
  const float* A = A4 + (size_t)m * CC_;
  float d = A[(size_t)threadIdx.x * 257];   // diag element
  __shared__ float sm[4];
  float r = waveRed(d);
  if ((threadIdx.x & 63) == 0) sm[threadIdx.x >> 6] = r;
  __syncthreads();
  float trace = sm[0] + sm[1] + sm[2] + sm[3];
  float sc = 1.1f * trace / (float)C_;
  if (s == 0 && threadIdx.x == 0) scal[m] = sc;
  float inv = 1.0f / sc;
  int i0 = s * (CC_ / 16);
  for (int i = i0 + threadIdx.x; i < i0 + CC_ / 16; i += 256) {
    Yp[(size_t)m * CC_ + i] = A[i] * inv;
    Yp[(size_t)(4 + m) * CC_ + i] = 0.f;
    Zp[(size_t)m * CC_ + i] = ((i >> 8) == (i & 255)) ? 1.0f : 0.0f;
    Zp[(size_t)(4 + m) * CC_ + i] = 0.f;
  }
}

// T = 3I - Z*Y, K-split: z in [0,8): m=z&3, kh=z>>2. Tp[kh] gets (kh==0?3I:0) - partial.
__global__ __launch_bounds__(256) void ns_stepA(
    const float* __restrict__ Zp, const float* __restrict__ Yp, float* __restrict__ Tp) {
  int z = blockIdx.z;
  int m = z & 3, kh = z >> 2;
  const float* A0 = Zp + (size_t)m * CC_;
  const float* A1 = Zp + (size_t)(4 + m) * CC_;
  const float* B0 = Yp + (size_t)m * CC_;
  const float* B1 = Yp + (size_t)(4 + m) * CC_;
  float* out = Tp + (size_t)(kh * 4 + m) * CC_;
  int i0 = blockIdx.y * 32, j0 = blockIdx.x * 32;
  int tx = threadIdx.x & 15, ty = threadIdx.x >> 4;
  __shared__ float sA[32][33], sB[32][33];
  float acc[2][2] = {};
  int k0e = kh * 128 + 128;
  for (int k0 = kh * 128; k0 < k0e; k0 += 32) {
    for (int l = threadIdx.x; l < 1024; l += 256) {
      int r = l >> 5, c = l & 31;
      size_t ia = (size_t)(i0 + r) * 256 + k0 + c;
      size_t ib = (size_t)(k0 + r) * 256 + j0 + c;
      sA[r][c] = A0[ia] + A1[ia];
      sB[r][c] = B0[ib] + B1[ib];
    }
    __syncthreads();
    #pragma unroll
    for (int kk = 0; kk < 32; kk++) {
      float a0 = sA[ty * 2][kk], a1 = sA[ty * 2 + 1][kk];
      float b0 = sB[kk][tx * 2], b1 = sB[kk][tx * 2 + 1];
      acc[0][0] += a0 * b0; acc[0][1] += a0 * b1;
      acc[1][0] += a1 * b0; acc[1][1] += a1 * b1;
    }
    __syncthreads();
  }
  for (int a = 0; a < 2; a++)
    for (int b = 0; b < 2; b++) {
      int i = i0 + ty * 2 + a, j = j0 + tx * 2 + b;
      float d = (kh == 0 && i == j) ? 3.0f : 0.0f;
      out[(size_t)i * 256 + j] = d - acc[a][b];
    }
}

// z in [0,16): m=z&3, kh=(z>>2)&1, doY=z<8.  Yn=0.5*Y*T ; Zn=0.5*T*Z (all K-split partials)
__global__ __launch_bounds__(256) void ns_stepB(
    const float* __restrict__ Yp, const float* __restrict__ Zp, const float* __restrict__ Tp,
    float* __restrict__ Ynp, float* __restrict__ Znp) {
  int z = blockIdx.z;
  int m = z & 3, kh = (z >> 2) & 1;
  bool doY = (z < 8);
  const float* A0 = doY ? (Yp + (size_t)m * CC_) : (Tp + (size_t)m * CC_);
  const float* A1 = doY ? (Yp + (size_t)(4 + m) * CC_) : (Tp + (size_t)(4 + m) * CC_);
  const float* B0 = doY ? (Tp + (size_t)m * CC_) : (Zp + (size_t)m * CC_);
  const float* B1 = doY ? (Tp + (size_t)(4 + m) * CC_) : (Zp + (size_t)(4 + m) * CC_);
  float* out = (doY ? Ynp : Znp) + (size_t)(kh * 4 + m) * CC_;
  int i0 = blockIdx.y * 32, j0 = blockIdx.x * 32;
  int tx = threadIdx.x & 15, ty = threadIdx.x >> 4;
  __shared__ float sA[32][33], sB[32][33];
  float acc[2][2] = {};
  int k0e = kh * 128 + 128;
  for (int k0 = kh * 128; k0 < k0e; k0 += 32) {
    for (int l = threadIdx.x; l < 1024; l += 256) {
      int r = l >> 5, c = l & 31;
      size_t ia = (size_t)(i0 + r) * 256 + k0 + c;
      size_t ib = (size_t)(k0 + r) * 256 + j0 + c;
      sA[r][c] = A0[ia] + A1[ia];
      sB[r][c] = B0[ib] + B1[ib];
    }
    __syncthreads();
    #pragma unroll
    for (int kk = 0; kk < 32; kk++) {
      float a0 = sA[ty * 2][kk], a1 = sA[ty * 2 + 1][kk];
      float b0 = sB[kk][tx * 2], b1 = sB[kk][tx * 2 + 1];
      acc[0][0] += a0 * b0; acc[0][1] += a0 * b1;
      acc[1][0] += a1 * b0; acc[1][1] += a1 * b1;
    }
    __syncthreads();
  }
  for (int a = 0; a < 2; a++)
    for (int b = 0; b < 2; b++) {
      int i = i0 + ty * 2 + a, j = j0 + tx * 2 + b;
      out[(size_t)i * 256 + j] = 0.5f * acc[a][b];
    }
}

// Apply whitening (Z/sqrt(s)) * f, write into zero-initialized padded buffers.
// m=0,1: content -> ncP [b][c][NP] ; m=2,3: style -> nsP [b][NP][c]
__global__ __launch_bounds__(256) void whiten_pad(
    const float* __restrict__ Zp, const float* __restrict__ scal,
    const float* __restrict__ fc, const float* __restrict__ fs,
    float* __restrict__ ncP, float* __restrict__ nsP) {
  int m = blockIdx.z;
  const float* W0 = Zp + (size_t)m * CC_;
  const float* W1 = Zp + (size_t)(4 + m) * CC_;
  const float* f = (m < 2) ? (fc + (size_t)m * C_ * N_) : (fs + (size_t)(m - 2) * C_ * N_);
  int c0 = blockIdx.y * 32, x0 = blockIdx.x * 32;
  int tx = threadIdx.x & 15, ty = threadIdx.x >> 4;
  __shared__ float sA[32][33], sB[32][33];
  float acc[2][2] = {};
  for (int k0 = 0; k0 < 256; k0 += 32) {
    for (int l = threadIdx.x; l < 1024; l += 256) {
      int r = l >> 5, c = l & 31;
      size_t ia = (size_t)(c0 + r) * 256 + k0 + c;
      sA[r][c] = W0[ia] + W1[ia];
      sB[r][c] = f[(size_t)(k0 + r) * N_ + x0 + c];
    }
    __syncthreads();
    #pragma unroll
    for (int kk = 0; kk < 32; kk++) {
      float a0 = sA[ty * 2][kk], a1 = sA[ty * 2 + 1][kk];
      float b0 = sB[kk][tx * 2], b1 = sB[kk][tx * 2 + 1];
      acc[0][0] += a0 * b0; acc[0][1] += a0 * b1;
      acc[1][0] += a1 * b0; acc[1][1] += a1 * b1;
    }
    __syncthreads();
  }
  float rs = rsqrtf(scal[m]);
  int b = (m < 2) ? m : (m - 2);
  for (int a = 0; a < 2; a++)
    for (int bb = 0; bb < 2; bb++) {
      int c = c0 + ty * 2 + a, x = x0 + tx * 2 + bb;
      int h = x / W_, w = x % W_;
      int pp = (h + 1) * PW_ + (w + 1);
      float val = acc[a][bb] * rs;
      if (m < 2) ncP[((size_t)b * C_ + c) * NP_ + pp] = val;
      else       nsP[((size_t)b * NP_ + pp) * C_ + c] = val;
    }
}

// q[b][p] = sum_c nsP[b][p][c]^2  (one wave per padded position)
__global__ __launch_bounds__(256) void q_kernel(const float* __restrict__ nsP, float* __restrict__ q) {
  int wid = (blockIdx.x * 256 + threadIdx.x) >> 6;
  int lane = threadIdx.x & 63;
  if (wid >= B_ * NP_) return;
  const float* v = nsP + (size_t)wid * C_;
  float acc = 0.f;
  #pragma unroll
  for (int c = lane; c < C_; c += 64) { float t = v[c]; acc += t * t; }
  acc = waveRed(acc);
  if (lane == 0) q[wid] = acc;
}

// kninv[b][n] = rsqrt( sum over 3x3 of q )
__global__ __launch_bounds__(256) void kninv_kernel(const float* __restrict__ q, float* __restrict__ kninv) {
  int t = blockIdx.x * 256 + threadIdx.x;
  if (t >= B_ * N_) return;
  int b = t / N_, n = t % N_;
  int hn = n / W_, wn = n % W_;
  const float* qb = q + (size_t)b * NP_ + hn * PW_ + wn;
  float s = 0.f;
  #pragma unroll
  for (int i = 0; i < 3; i++)
    #pragma unroll
    for (int j = 0; j < 3; j++) s += qb[i * PW_ + j];
  kninv[t] = rsqrtf(s);
}

// M = nsP[b] (2500x256) * ncP[b] (256x2500) -> M (2500x2500)
__global__ __launch_bounds__(256) void m_kernel(
    const float* __restrict__ Asty, const float* __restrict__ Bcon, float* __restrict__ M) {
  int i0 = blockIdx.y * 64, j0 = blockIdx.x * 64;
  int tx = threadIdx.x & 15, ty = threadIdx.x >> 4;
  __shared__ float sA[64][17], sB[16][65];
  float acc[4][4] = {};
  for (int k0 = 0; k0 < 256; k0 += 16) {
    for (int l = threadIdx.x; l < 1024; l += 256) {
      int r = l >> 4, kk = l & 15;
      int row = i0 + r;
      sA[r][kk] = (row < NP_) ? Asty[(size_t)row * C_ + k0 + kk] : 0.f;
    }
    for (int l = threadIdx.x; l < 1024; l += 256) {
      int kk = l >> 6, c = l & 63;
      int col = j0 + c;
      sB[kk][c] = (col < NP_) ? Bcon[(size_t)(k0 + kk) * NP_ + col] : 0.f;
    }
    __syncthreads();
    #pragma unroll
    for (int kk = 0; kk < 16; kk++) {
      float a[4], bb[4];
      #pragma unroll
      for (int u = 0; u < 4; u++) a[u] = sA[ty * 4 + u][kk];
      #pragma unroll
      for (int u = 0; u < 4; u++) bb[u] = sB[kk][tx * 4 + u];
      #pragma unroll
      for (int u = 0; u < 4; u++)
        #pragma unroll
        for (int v = 0; v < 4; v++) acc[u][v] += a[u] * bb[v];
    }
    __syncthreads();
  }
  for (int u = 0; u < 4; u++)
    for (int v = 0; v < 4; v++) {
      int i = i0 + ty * 4 + u, j = j0 + tx * 4 + v;
      if (i < NP_ && j < NP_) M[(size_t)i * NP_ + j] = acc[u][v];
    }
}

// Partial argmax over an n-chunk for each content position m.
__global__ __launch_bounds__(256) void score_kernel(
    const float* __restrict__ M, const float* __restrict__ kninv,
    float* __restrict__ pval, int* __restrict__ pidx, int b) {
  int m = blockIdx.x * 256 + threadIdx.x;     // 0..N-1
  int h = m / W_, w = m % W_;
  int cm = h * PW_ + w;
  int n0 = blockIdx.y * NC_;
  const float* kni = kninv + (size_t)b * N_;
  float best = -3.4e38f;
  int bidx = n0;
  for (int n = n0; n < n0 + NC_; n++) {
    int hn = n / W_, wn = n % W_;
    int rn = hn * PW_ + wn;
    const float* base = M + (size_t)rn * NP_ + cm;
    float s = 0.f;
    #pragma unroll
    for (int i = 0; i < 3; i++)
      #pragma unroll
      for (int j = 0; j < 3; j++) s += base[(size_t)(i * PW_ + j) * (NP_ + 1)];
    s *= kni[n];
    if (s > best) { best = s; bidx = n; }
  }
  pval[((size_t)b * NCH_ + blockIdx.y) * N_ + m] = best;
  pidx[((size_t)b * NCH_ + blockIdx.y) * N_ + m] = bidx;
}

// Final argmax across chunks (ascending => first-max wins, matches jnp.argmax)
__global__ __launch_bounds__(256) void argmax_final(
    const float* __restrict__ pval, const int* __restrict__ pidx, int* __restrict__ idxb) {
  int t = blockIdx.x * 256 + threadIdx.x;
  if (t >= B_ * N_) return;
  int b = t / N_, m = t % N_;
  float best = -3.4e38f; int bidx = 0;
  for (int ch = 0; ch < NCH_; ch++) {
    float v = pval[((size_t)b * NCH_ + ch) * N_ + m];
    int i = pidx[((size_t)b * NCH_ + ch) * N_ + m];
    if (v > best) { best = v; bidx = i; }
  }
  idxb[t] = bidx;
}

// Overlap-add reassembly: recon[b][m][c] layout (position-major)
__global__ __launch_bounds__(256) void reassemble_kernel(
    const float* __restrict__ nsP, const int* __restrict__ idxb, float* __restrict__ recon) {
  int bm = blockIdx.x;
  int b = bm / N_, m = bm % N_;
  int h = m / W_, w = m % W_;
  int c = threadIdx.x;
  float acc = 0.f; int cnt = 0;
  for (int di = 0; di < 3; di++) {
    int hs = h + 1 - di; if (hs < 0 || hs >= H_) continue;
    for (int dj = 0; dj < 3; dj++) {
      int ws = w + 1 - dj; if (ws < 0 || ws >= W_) continue;
      int n = idxb[(size_t)b * N_ + hs * W_ + ws];
      int hn = n / W_, wn = n % W_;
      int pp = (hn + di) * PW_ + (wn + dj);
      acc += nsP[((size_t)b * NP_ + pp) * C_ + c];
      cnt++;
    }
  }
  recon[((size_t)b * N_ + m) * C_ + c] = acc / (float)cnt;
}

// Partial column sums of recon over x-chunks
__global__ __launch_bounds__(256) void rmean_part(const float* __restrict__ recon, float* __restrict__ pmr) {
  int b = blockIdx.y, ch = blockIdx.x, c = threadIdx.x;
  float acc = 0.f;
  int x0 = ch * (N_ / 16);
  for (int x = x0; x < x0 + (N_ / 16); x++) acc += recon[((size_t)b * N_ + x) * C_ + c];
  pmr[((size_t)b * 16 + ch) * C_ + c] = acc;
}

__global__ __launch_bounds__(256) void rmean_fin(const float* __restrict__ pmr, float* __restrict__ mr) {
  int b = blockIdx.x, c = threadIdx.x;
  float acc = 0.f;
  for (int ch = 0; ch < 16; ch++) acc += pmr[((size_t)b * 16 + ch) * C_ + c];
  mr[(size_t)b * C_ + c] = acc * (1.0f / N_);
}

// stylized = sqrt(cov_s)*(recon-mr) + mean_s ; out = (1-ss)*content + ss*stylized
__global__ __launch_bounds__(256) void color_blend(
    const float* __restrict__ Yp, const float* __restrict__ scal,
    const float* __restrict__ recon, const float* __restrict__ mr,
    const float* __restrict__ msty, const float* __restrict__ content,
    const float* __restrict__ ssp, float* __restrict__ out) {
  int b = blockIdx.z;
  const float* W0 = Yp + (size_t)(2 + b) * CC_;
  const float* W1 = Yp + (size_t)(4 + 2 + b) * CC_;
  int c0 = blockIdx.y * 32, x0 = blockIdx.x * 32;
  int tx = threadIdx.x & 15, ty = threadIdx.x >> 4;
  __shared__ float sA[32][33], sB[32][33];
  float acc[2][2] = {};
  for (int k0 = 0; k0 < 256; k0 += 32) {
    for (int l = threadIdx.x; l < 1024; l += 256) {
      int r = l >> 5, c = l & 31;
      size_t ia = (size_t)(c0 + r) * 256 + k0 + c;
      sA[r][c] = W0[ia] + W1[ia];
    }
    for (int l = threadIdx.x; l < 1024; l += 256) {
      int dd = l & 31, xx = l >> 5;
      sB[dd][xx] = recon[((size_t)b * N_ + x0 + xx) * C_ + k0 + dd] - mr[(size_t)b * C_ + k0 + dd];
    }
    __syncthreads();
    #pragma unroll
    for (int kk = 0; kk < 32; kk++) {
      float a0 = sA[ty * 2][kk], a1 = sA[ty * 2 + 1][kk];
      float b0 = sB[kk][tx * 2], b1 = sB[kk][tx * 2 + 1];
      acc[0][0] += a0 * b0; acc[0][1] += a0 * b1;
      acc[1][0] += a1 * b0; acc[1][1] += a1 * b1;
    }
    __syncthreads();
  }
  float sq = sqrtf(scal[2 + b]);
  float ss = ssp[0];
  for (int u = 0; u < 2; u++)
    for (int v = 0; v < 2; v++) {
      int c = c0 + ty * 2 + u, x = x0 + tx * 2 + v;
      float sty = acc[u][v] * sq + msty[(size_t)b * C_ + c];
      size_t o = ((size_t)b * C_ + c) * N_ + x;
      out[o] = (1.0f - ss) * content[o] + ss * sty;
    }
}

// ---------------- host launch ----------------
extern "C" void kernel_launch(void* const* d_in, const int* in_sizes, int n_in,
                              void* d_out, int out_size, void* d_ws, size_t ws_size,
                              hipStream_t stream) {
  (void)in_sizes; (void)n_in; (void)out_size; (void)ws_size;
  const float* content = (const float*)d_in[0];
  const float* style   = (const float*)d_in[1];
  const float* ssp     = (const float*)d_in[2];   // style_strength scalar
  float* out = (float*)d_out;
  float* W = (float*)d_ws;

  // workspace layout (floats)
  size_t off = 0;
  float* fc   = W + off; off += (size_t)B_ * C_ * N_;
  float* fs   = W + off; off += (size_t)B_ * C_ * N_;   // recon aliases fs later
  float* nsP  = W + off; off += (size_t)B_ * NP_ * C_;
  float* ncP  = W + off; off += (size_t)B_ * C_ * NP_;
  float* A4   = W + off; off += (size_t)4 * CC_;
  float* YpA  = W + off; off += (size_t)8 * CC_;
  float* YpB  = W + off; off += (size_t)8 * CC_;
  float* ZpA  = W + off; off += (size_t)8 * CC_;
  float* ZpB  = W + off; off += (size_t)8 * CC_;
  float* Tp   = W + off; off += (size_t)8 * CC_;
  float* scal = W + off; off += 4;
  float* msty = W + off; off += (size_t)B_ * C_;
  float* mr   = W + off; off += (size_t)B_ * C_;
  float* pmr  = W + off; off += (size_t)B_ * 16 * C_;
  float* q    = W + off; off += (size_t)B_ * NP_;
  float* kni  = W + off; off += (size_t)B_ * N_;
  float* pval = W + off; off += (size_t)B_ * NCH_ * N_;
  float* Mb   = W + off; off += (size_t)NP_ * NP_;   // pcov aliases Mb (dead before m_kernel)
  int* pidx = (int*)(W + off); off += (size_t)B_ * NCH_ * N_;
  int* idxb = (int*)(W + off); off += (size_t)B_ * N_;
  float* pcov = Mb;          // 9*4*CC = 2.36M floats <= 6.25M floats of Mb
  float* recon = fs;         // fs dead after whiten_pad; recon written after

  // zero padded buffers (borders must stay 0)
  hipMemsetAsync(nsP, 0, (size_t)B_ * NP_ * C_ * sizeof(float), stream);
  hipMemsetAsync(ncP, 0, (size_t)B_ * C_ * NP_ * sizeof(float), stream);

  center_kernel<<<2 * B_ * C_, 256, 0, stream>>>(content, style, fc, fs, msty);
  cov_kernel<<<dim3(8, 8, 4 * KCH_), 256, 0, stream>>>(fc, fs, pcov);
  covreduce<<<4 * CC_ / 256, 256, 0, stream>>>(pcov, A4);
  ns_init<<<dim3(16, 4), 256, 0, stream>>>(A4, YpA, ZpA, scal);

  float *Ycur = YpA, *Zcur = ZpA, *Yalt = YpB, *Zalt = ZpB;
  for (int it = 0; it < NSIT_; it++) {
    ns_stepA<<<dim3(8, 8, 8), 256, 0, stream>>>(Zcur, Ycur, Tp);
    ns_stepB<<<dim3(8, 8, 16), 256, 0, stream>>>(Ycur, Zcur, Tp, Yalt, Zalt);
    float* t;
    t = Ycur; Ycur = Yalt; Yalt = t;
    t = Zcur; Zcur = Zalt; Zalt = t;
  }

  whiten_pad<<<dim3(N_ / 32, 8, 4), 256, 0, stream>>>(Zcur, scal, fc, fs, ncP, nsP);
  q_kernel<<<(B_ * NP_ + 3) / 4, 256, 0, stream>>>(nsP, q);
  kninv_kernel<<<(B_ * N_ + 255) / 256, 256, 0, stream>>>(q, kni);

  for (int b = 0; b < B_; b++) {
    m_kernel<<<dim3((NP_ + 63) / 64, (NP_ + 63) / 64), 256, 0, stream>>>(
        nsP + (size_t)b * NP_ * C_, ncP + (size_t)b * C_ * NP_, Mb);
    score_kernel<<<dim3(N_ / 256, NCH_), 256, 0, stream>>>(Mb, kni, pval, pidx, b);
  }
  argmax_final<<<(B_ * N_ + 255) / 256, 256, 0, stream>>>(pval, pidx, idxb);
  reassemble_kernel<<<B_ * N_, 256, 0, stream>>>(nsP, idxb, recon);
  rmean_part<<<dim3(16, B_), 256, 0, stream>>>(recon, pmr);
  rmean_fin<<<B_, 256, 0, stream>>>(pmr, mr);
  color_blend<<<dim3(N_ / 32, 8, B_), 256, 0, stream>>>(
      Ycur, scal, recon, mr, msty, content, ssp, out);
}

// Round 3
// 463.303 us; speedup vs baseline: 2.1161x; 1.4237x over previous
//
#include <hip/hip_runtime.h>

// Problem constants (setup_inputs: B=2, C=256, H=W=48, p=3)
constexpr int B_  = 2;
constexpr int C_  = 256;
constexpr int H_  = 48;
constexpr int W_  = 48;
constexpr int N_  = H_ * W_;          // 2304
constexpr int PH_ = H_ + 2;           // 50
constexpr int PW_ = W_ + 2;           // 50
constexpr int NP_ = PH_ * PW_;        // 2500
constexpr int CC_ = C_ * C_;          // 65536
constexpr int NCH_ = 36;              // n-chunks for score partial argmax
constexpr int NC_  = N_ / NCH_;       // 64
constexpr int NSIT_ = 7;              // Newton-Schulz iterations (e7 ~ 1e-17)
constexpr int KCH_ = 9;               // cov K-chunks (2304 = 9*256)

// ---------------- reduction helpers ----------------
__device__ inline float waveRed(float v) {
  #pragma unroll
  for (int o = 32; o > 0; o >>= 1) v += __shfl_down(v, o);
  return v;
}

// 16-FMA inner step on staged tiles
#define GEMM64_COMPUTE(sAT, sB, acc, ty, tx)                        \
  _Pragma("unroll")                                                 \
  for (int kk = 0; kk < 16; kk++) {                                 \
    float4 a = *(const float4*)&sAT[kk][(ty) * 4];                  \
    float4 b = *(const float4*)&sB[kk][(tx) * 4];                   \
    acc[0][0] += a.x * b.x; acc[0][1] += a.x * b.y;                 \
    acc[0][2] += a.x * b.z; acc[0][3] += a.x * b.w;                 \
    acc[1][0] += a.y * b.x; acc[1][1] += a.y * b.y;                 \
    acc[1][2] += a.y * b.z; acc[1][3] += a.y * b.w;                 \
    acc[2][0] += a.z * b.x; acc[2][1] += a.z * b.y;                 \
    acc[2][2] += a.z * b.z; acc[2][3] += a.z * b.w;                 \
    acc[3][0] += a.w * b.x; acc[3][1] += a.w * b.y;                 \
    acc[3][2] += a.w * b.z; acc[3][3] += a.w * b.w;                 \
  }

// ---------------- kernels ----------------

// Per-(b,c) mean over N, write centered rows. which=0: content->fc, 1: style->fs
__global__ __launch_bounds__(256) void center_kernel(
    const float* __restrict__ content, const float* __restrict__ style,
    float* __restrict__ fc, float* __restrict__ fs, float* __restrict__ mean_s) {
  int t = blockIdx.x;
  int which = t / (B_ * C_);
  int bc = t % (B_ * C_);
  const float* src = which ? style : content;
  float* dst = which ? fs : fc;
  const float* row = src + (size_t)bc * N_;
  float acc = 0.f;
  for (int i = threadIdx.x; i < N_; i += 256) acc += row[i];
  __shared__ float sm[4];
  float r = waveRed(acc);
  if ((threadIdx.x & 63) == 0) sm[threadIdx.x >> 6] = r;
  __syncthreads();
  float mean = (sm[0] + sm[1] + sm[2] + sm[3]) * (1.0f / N_);
  for (int i = threadIdx.x; i < N_; i += 256) dst[(size_t)bc * N_ + i] = row[i] - mean;
  if (which == 1 && threadIdx.x == 0) mean_s[bc] = mean;
}

// K-split covariance partials: z = ci*4+m. 64x64 tile, both operands transposed-staged.
__global__ __launch_bounds__(256) void cov_kernel(
    const float* __restrict__ fc, const float* __restrict__ fs, float* __restrict__ pcov) {
  int z = blockIdx.z;
  int m = z & 3, ci = z >> 2;
  const float* f = (m < 2) ? (fc + (size_t)m * C_ * N_) : (fs + (size_t)(m - 2) * C_ * N_);
  int i0 = blockIdx.y * 64, j0 = blockIdx.x * 64;
  int t = threadIdx.x;
  int tx = t & 15, ty = t >> 4;
  int sr = t >> 2, skq = t & 3;
  __shared__ float sAT[16][68], sB[16][68];
  float acc[4][4] = {};
  int k0e = ci * 256 + 256;
  for (int k0 = ci * 256; k0 < k0e; k0 += 16) {
    float4 av = *(const float4*)&f[(size_t)(i0 + sr) * N_ + k0 + skq * 4];
    float4 bv = *(const float4*)&f[(size_t)(j0 + sr) * N_ + k0 + skq * 4];
    __syncthreads();
    sAT[skq * 4 + 0][sr] = av.x; sAT[skq * 4 + 1][sr] = av.y;
    sAT[skq * 4 + 2][sr] = av.z; sAT[skq * 4 + 3][sr] = av.w;
    sB[skq * 4 + 0][sr] = bv.x;  sB[skq * 4 + 1][sr] = bv.y;
    sB[skq * 4 + 2][sr] = bv.z;  sB[skq * 4 + 3][sr] = bv.w;
    __syncthreads();
    GEMM64_COMPUTE(sAT, sB, acc, ty, tx)
  }
  float* out = pcov + ((size_t)ci * 4 + m) * CC_;
  for (int u = 0; u < 4; u++)
    for (int v = 0; v < 4; v++)
      out[(size_t)(i0 + ty * 4 + u) * C_ + (j0 + tx * 4 + v)] = acc[u][v];
}

// A4[m] = (sum_ci pcov[ci][m]) / (N-1)
__global__ __launch_bounds__(256) void covreduce(
    const float* __restrict__ pcov, float* __restrict__ A4) {
  int t = blockIdx.x * 256 + threadIdx.x;
  float acc = 0.f;
  #pragma unroll
  for (int ci = 0; ci < KCH_; ci++) acc += pcov[(size_t)ci * 4 * CC_ + t];
  A4[t] = acc * (1.0f / (float)(N_ - 1));
}

// Init 4-partial sets: Yp[p=0]=A/s (others 0), Zp[p=0]=I (others 0). Partial p of matrix m
// lives at offset (p*4+m)*CC.
__global__ __launch_bounds__(256) void ns_init(
    const float* __restrict__ A4, float* __restrict__ Yp, float* __restrict__ Zp,
    float* __restrict__ scal) {
  int m = blockIdx.y, s = blockIdx.x;
  const float* A = A4 + (size_t)m * CC_;
  float d = A[(size_t)threadIdx.x * 257];
  __shared__ float sm[4];
  float r = waveRed(d);
  if ((threadIdx.x & 63) == 0) sm[threadIdx.x >> 6] = r;
  __syncthreads();
  float trace = sm[0] + sm[1] + sm[2] + sm[3];
  float sc = 1.1f * trace / (float)C_;
  if (s == 0 && threadIdx.x == 0) scal[m] = sc;
  float inv = 1.0f / sc;
  int i0 = s * (CC_ / 16);
  for (int i = i0 + threadIdx.x; i < i0 + CC_ / 16; i += 256) {
    Yp[(size_t)m * CC_ + i] = A[i] * inv;
    Zp[(size_t)m * CC_ + i] = ((i >> 8) == (i & 255)) ? 1.0f : 0.0f;
    #pragma unroll
    for (int p = 1; p < 4; p++) {
      Yp[(size_t)(p * 4 + m) * CC_ + i] = 0.f;
      Zp[(size_t)(p * 4 + m) * CC_ + i] = 0.f;
    }
  }
}

// T_kh = (kh==0 ? 3I : 0) - (sum_p Z_p)(sum_p Y_p) restricted to K in [kh*64,(kh+1)*64)
// grid (4,4,16): z = kh*4+m
__global__ __launch_bounds__(256) void ns_stepA(
    const float* __restrict__ Zp, const float* __restrict__ Yp, float* __restrict__ Tp) {
  int z = blockIdx.z;
  int m = z & 3, kh = z >> 2;
  int i0 = blockIdx.y * 64, j0 = blockIdx.x * 64;
  int t = threadIdx.x;
  int tx = t & 15, ty = t >> 4;
  int sr = t >> 2, skq = t & 3;      // A-staging
  int bkk = t & 15, bc4 = t >> 4;    // B-staging
  __shared__ float sAT[16][68], sB[16][68];
  float acc[4][4] = {};
  int k0e = kh * 64 + 64;
  for (int k0 = kh * 64; k0 < k0e; k0 += 16) {
    float4 av = {0,0,0,0}, bv = {0,0,0,0};
    #pragma unroll
    for (int p = 0; p < 4; p++) {
      float4 a = *(const float4*)&Zp[(size_t)(p * 4 + m) * CC_ + (size_t)(i0 + sr) * 256 + k0 + skq * 4];
      float4 b = *(const float4*)&Yp[(size_t)(p * 4 + m) * CC_ + (size_t)(k0 + bkk) * 256 + j0 + bc4 * 4];
      av.x += a.x; av.y += a.y; av.z += a.z; av.w += a.w;
      bv.x += b.x; bv.y += b.y; bv.z += b.z; bv.w += b.w;
    }
    __syncthreads();
    sAT[skq * 4 + 0][sr] = av.x; sAT[skq * 4 + 1][sr] = av.y;
    sAT[skq * 4 + 2][sr] = av.z; sAT[skq * 4 + 3][sr] = av.w;
    *(float4*)&sB[bkk][bc4 * 4] = bv;
    __syncthreads();
    GEMM64_COMPUTE(sAT, sB, acc, ty, tx)
  }
  float* out = Tp + (size_t)z * CC_;
  for (int u = 0; u < 4; u++)
    for (int v = 0; v < 4; v++) {
      int i = i0 + ty * 4 + u, j = j0 + tx * 4 + v;
      float d = (kh == 0 && i == j) ? 3.0f : 0.0f;
      out[(size_t)i * 256 + j] = d - acc[u][v];
    }
}

// grid (4,4,32): m=z&3, kh=(z>>2)&3, doY=z<16. Yn_kh=0.5*Y*T | Zn_kh=0.5*T*Z (K-restricted)
__global__ __launch_bounds__(256) void ns_stepB(
    const float* __restrict__ Yp, const float* __restrict__ Zp, const float* __restrict__ Tp,
    float* __restrict__ Ynp, float* __restrict__ Znp) {
  int z = blockIdx.z;
  int m = z & 3, kh = (z >> 2) & 3;
  bool doY = (z < 16);
  const float* Abase = doY ? Yp : Tp;
  const float* Bbase = doY ? Tp : Zp;
  float* out = (doY ? Ynp : Znp) + (size_t)(kh * 4 + m) * CC_;
  int i0 = blockIdx.y * 64, j0 = blockIdx.x * 64;
  int t = threadIdx.x;
  int tx = t & 15, ty = t >> 4;
  int sr = t >> 2, skq = t & 3;
  int bkk = t & 15, bc4 = t >> 4;
  __shared__ float sAT[16][68], sB[16][68];
  float acc[4][4] = {};
  int k0e = kh * 64 + 64;
  for (int k0 = kh * 64; k0 < k0e; k0 += 16) {
    float4 av = {0,0,0,0}, bv = {0,0,0,0};
    #pragma unroll
    for (int p = 0; p < 4; p++) {
      float4 a = *(const float4*)&Abase[(size_t)(p * 4 + m) * CC_ + (size_t)(i0 + sr) * 256 + k0 + skq * 4];
      float4 b = *(const float4*)&Bbase[(size_t)(p * 4 + m) * CC_ + (size_t)(k0 + bkk) * 256 + j0 + bc4 * 4];
      av.x += a.x; av.y += a.y; av.z += a.z; av.w += a.w;
      bv.x += b.x; bv.y += b.y; bv.z += b.z; bv.w += b.w;
    }
    __syncthreads();
    sAT[skq * 4 + 0][sr] = av.x; sAT[skq * 4 + 1][sr] = av.y;
    sAT[skq * 4 + 2][sr] = av.z; sAT[skq * 4 + 3][sr] = av.w;
    *(float4*)&sB[bkk][bc4 * 4] = bv;
    __syncthreads();
    GEMM64_COMPUTE(sAT, sB, acc, ty, tx)
  }
  for (int u = 0; u < 4; u++)
    for (int v = 0; v < 4; v++) {
      int i = i0 + ty * 4 + u, j = j0 + tx * 4 + v;
      out[(size_t)i * 256 + j] = 0.5f * acc[u][v];
    }
}

// (sum_p Z_p)/sqrt(s) * f -> padded buffers. m<2: content -> ncP [b][c][NP];
// m>=2: style -> nsP [b][NP][c].  grid (36,4,4)
__global__ __launch_bounds__(256) void whiten_pad(
    const float* __restrict__ Zp, const float* __restrict__ scal,
    const float* __restrict__ fc, const float* __restrict__ fs,
    float* __restrict__ ncP, float* __restrict__ nsP) {
  int m = blockIdx.z;
  const float* f = (m < 2) ? (fc + (size_t)m * C_ * N_) : (fs + (size_t)(m - 2) * C_ * N_);
  int c0 = blockIdx.y * 64, x0 = blockIdx.x * 64;
  int t = threadIdx.x;
  int tx = t & 15, ty = t >> 4;
  int sr = t >> 2, skq = t & 3;
  int bkk = t & 15, bc4 = t >> 4;
  __shared__ float sAT[16][68], sB[16][68];
  float acc[4][4] = {};
  for (int k0 = 0; k0 < 256; k0 += 16) {
    float4 av = {0,0,0,0};
    #pragma unroll
    for (int p = 0; p < 4; p++) {
      float4 a = *(const float4*)&Zp[(size_t)(p * 4 + m) * CC_ + (size_t)(c0 + sr) * 256 + k0 + skq * 4];
      av.x += a.x; av.y += a.y; av.z += a.z; av.w += a.w;
    }
    float4 bv = *(const float4*)&f[(size_t)(k0 + bkk) * N_ + x0 + bc4 * 4];
    __syncthreads();
    sAT[skq * 4 + 0][sr] = av.x; sAT[skq * 4 + 1][sr] = av.y;
    sAT[skq * 4 + 2][sr] = av.z; sAT[skq * 4 + 3][sr] = av.w;
    *(float4*)&sB[bkk][bc4 * 4] = bv;
    __syncthreads();
    GEMM64_COMPUTE(sAT, sB, acc, ty, tx)
  }
  float rs = rsqrtf(scal[m]);
  int b = (m < 2) ? m : (m - 2);
  for (int u = 0; u < 4; u++)
    for (int v = 0; v < 4; v++) {
      int c = c0 + ty * 4 + u, x = x0 + tx * 4 + v;
      int h = x / W_, w = x % W_;
      int pp = (h + 1) * PW_ + (w + 1);
      float val = acc[u][v] * rs;
      if (m < 2) ncP[((size_t)b * C_ + c) * NP_ + pp] = val;
      else       nsP[((size_t)b * NP_ + pp) * C_ + c] = val;
    }
}

// q[b][p] = sum_c nsP[b][p][c]^2
__global__ __launch_bounds__(256) void q_kernel(const float* __restrict__ nsP, float* __restrict__ q) {
  int wid = (blockIdx.x * 256 + threadIdx.x) >> 6;
  int lane = threadIdx.x & 63;
  if (wid >= B_ * NP_) return;
  const float* v = nsP + (size_t)wid * C_;
  float acc = 0.f;
  #pragma unroll
  for (int c = lane; c < C_; c += 64) { float t = v[c]; acc += t * t; }
  acc = waveRed(acc);
  if (lane == 0) q[wid] = acc;
}

// kninv[b][n] = rsqrt( sum over 3x3 of q )
__global__ __launch_bounds__(256) void kninv_kernel(const float* __restrict__ q, float* __restrict__ kninv) {
  int t = blockIdx.x * 256 + threadIdx.x;
  if (t >= B_ * N_) return;
  int b = t / N_, n = t % N_;
  int hn = n / W_, wn = n % W_;
  const float* qb = q + (size_t)b * NP_ + hn * PW_ + wn;
  float s = 0.f;
  #pragma unroll
  for (int i = 0; i < 3; i++)
    #pragma unroll
    for (int j = 0; j < 3; j++) s += qb[i * PW_ + j];
  kninv[t] = rsqrtf(s);
}

// M = nsP[b] (2500x256) * ncP[b] (256x2500). 64x64 tiles, grid (40,40).
__global__ __launch_bounds__(256) void m_kernel(
    const float* __restrict__ Asty, const float* __restrict__ Bcon, float* __restrict__ M) {
  int i0 = blockIdx.y * 64, j0 = blockIdx.x * 64;
  int t = threadIdx.x;
  int tx = t & 15, ty = t >> 4;
  int sr = t >> 2, skq = t & 3;
  int bkk = t & 15, bc4 = t >> 4;
  __shared__ float sAT[16][68], sB[16][68];
  float acc[4][4] = {};
  bool arow_ok = (i0 + sr) < NP_;
  int bcol = j0 + bc4 * 4;
  for (int k0 = 0; k0 < 256; k0 += 16) {
    float4 av = {0,0,0,0}, bv = {0,0,0,0};
    if (arow_ok) av = *(const float4*)&Asty[(size_t)(i0 + sr) * C_ + k0 + skq * 4];
    if (bcol + 3 < NP_) bv = *(const float4*)&Bcon[(size_t)(k0 + bkk) * NP_ + bcol];
    else {
      float tmp[4] = {0,0,0,0};
      for (int j = 0; j < 4; j++) if (bcol + j < NP_) tmp[j] = Bcon[(size_t)(k0 + bkk) * NP_ + bcol + j];
      bv.x = tmp[0]; bv.y = tmp[1]; bv.z = tmp[2]; bv.w = tmp[3];
    }
    __syncthreads();
    sAT[skq * 4 + 0][sr] = av.x; sAT[skq * 4 + 1][sr] = av.y;
    sAT[skq * 4 + 2][sr] = av.z; sAT[skq * 4 + 3][sr] = av.w;
    *(float4*)&sB[bkk][bc4 * 4] = bv;
    __syncthreads();
    GEMM64_COMPUTE(sAT, sB, acc, ty, tx)
  }
  for (int u = 0; u < 4; u++)
    for (int v = 0; v < 4; v++) {
      int i = i0 + ty * 4 + u, j = j0 + tx * 4 + v;
      if (i < NP_ && j < NP_) M[(size_t)i * NP_ + j] = acc[u][v];
    }
}

// Partial argmax over an n-chunk for each content position m.
__global__ __launch_bounds__(256) void score_kernel(
    const float* __restrict__ M, const float* __restrict__ kninv,
    float* __restrict__ pval, int* __restrict__ pidx, int b) {
  int m = blockIdx.x * 256 + threadIdx.x;
  int h = m / W_, w = m % W_;
  int cm = h * PW_ + w;
  int n0 = blockIdx.y * NC_;
  const float* kni = kninv + (size_t)b * N_;
  float best = -3.4e38f;
  int bidx = n0;
  for (int n = n0; n < n0 + NC_; n++) {
    int hn = n / W_, wn = n % W_;
    int rn = hn * PW_ + wn;
    const float* base = M + (size_t)rn * NP_ + cm;
    float s = 0.f;
    #pragma unroll
    for (int i = 0; i < 3; i++)
      #pragma unroll
      for (int j = 0; j < 3; j++) s += base[(size_t)(i * PW_ + j) * (NP_ + 1)];
    s *= kni[n];
    if (s > best) { best = s; bidx = n; }
  }
  pval[((size_t)b * NCH_ + blockIdx.y) * N_ + m] = best;
  pidx[((size_t)b * NCH_ + blockIdx.y) * N_ + m] = bidx;
}

// Final argmax across chunks (ascending => first-max wins, matches jnp.argmax)
__global__ __launch_bounds__(256) void argmax_final(
    const float* __restrict__ pval, const int* __restrict__ pidx, int* __restrict__ idxb) {
  int t = blockIdx.x * 256 + threadIdx.x;
  if (t >= B_ * N_) return;
  int b = t / N_, m = t % N_;
  float best = -3.4e38f; int bidx = 0;
  for (int ch = 0; ch < NCH_; ch++) {
    float v = pval[((size_t)b * NCH_ + ch) * N_ + m];
    int i = pidx[((size_t)b * NCH_ + ch) * N_ + m];
    if (v > best) { best = v; bidx = i; }
  }
  idxb[t] = bidx;
}

// Overlap-add reassembly: recon[b][m][c] (position-major)
__global__ __launch_bounds__(256) void reassemble_kernel(
    const float* __restrict__ nsP, const int* __restrict__ idxb, float* __restrict__ recon) {
  int bm = blockIdx.x;
  int b = bm / N_, m = bm % N_;
  int h = m / W_, w = m % W_;
  int c = threadIdx.x;
  float acc = 0.f; int cnt = 0;
  for (int di = 0; di < 3; di++) {
    int hs = h + 1 - di; if (hs < 0 || hs >= H_) continue;
    for (int dj = 0; dj < 3; dj++) {
      int ws = w + 1 - dj; if (ws < 0 || ws >= W_) continue;
      int n = idxb[(size_t)b * N_ + hs * W_ + ws];
      int hn = n / W_, wn = n % W_;
      int pp = (hn + di) * PW_ + (wn + dj);
      acc += nsP[((size_t)b * NP_ + pp) * C_ + c];
      cnt++;
    }
  }
  recon[((size_t)b * N_ + m) * C_ + c] = acc / (float)cnt;
}

// Partial column sums of recon over x-chunks
__global__ __launch_bounds__(256) void rmean_part(const float* __restrict__ recon, float* __restrict__ pmr) {
  int b = blockIdx.y, ch = blockIdx.x, c = threadIdx.x;
  float acc = 0.f;
  int x0 = ch * (N_ / 16);
  for (int x = x0; x < x0 + (N_ / 16); x++) acc += recon[((size_t)b * N_ + x) * C_ + c];
  pmr[((size_t)b * 16 + ch) * C_ + c] = acc;
}

__global__ __launch_bounds__(256) void rmean_fin(const float* __restrict__ pmr, float* __restrict__ mr) {
  int b = blockIdx.x, c = threadIdx.x;
  float acc = 0.f;
  for (int ch = 0; ch < 16; ch++) acc += pmr[((size_t)b * 16 + ch) * C_ + c];
  mr[(size_t)b * C_ + c] = acc * (1.0f / N_);
}

// stylized = sqrt(cov_s)*(recon-mr) + mean_s ; out = (1-ss)*content + ss*stylized
// grid (36,4,2). A = sum_p Y_p (style matrix m=2+b)
__global__ __launch_bounds__(256) void color_blend(
    const float* __restrict__ Yp, const float* __restrict__ scal,
    const float* __restrict__ recon, const float* __restrict__ mr,
    const float* __restrict__ msty, const float* __restrict__ content,
    const float* __restrict__ ssp, float* __restrict__ out) {
  int b = blockIdx.z;
  int m = 2 + b;
  int c0 = blockIdx.y * 64, x0 = blockIdx.x * 64;
  int t = threadIdx.x;
  int tx = t & 15, ty = t >> 4;
  int sr = t >> 2, skq = t & 3;
  __shared__ float sAT[16][68], sB[16][68];
  float acc[4][4] = {};
  for (int k0 = 0; k0 < 256; k0 += 16) {
    float4 av = {0,0,0,0};
    #pragma unroll
    for (int p = 0; p < 4; p++) {
      float4 a = *(const float4*)&Yp[(size_t)(p * 4 + m) * CC_ + (size_t)(c0 + sr) * 256 + k0 + skq * 4];
      av.x += a.x; av.y += a.y; av.z += a.z; av.w += a.w;
    }
    // B staged transposed from recon rows (stride C along k): thread (xx=sr, kq=skq)
    float4 bm4 = *(const float4*)&mr[(size_t)b * C_ + k0 + skq * 4];
    float4 bv = *(const float4*)&recon[((size_t)b * N_ + x0 + sr) * C_ + k0 + skq * 4];
    bv.x -= bm4.x; bv.y -= bm4.y; bv.z -= bm4.z; bv.w -= bm4.w;
    __syncthreads();
    sAT[skq * 4 + 0][sr] = av.x; sAT[skq * 4 + 1][sr] = av.y;
    sAT[skq * 4 + 2][sr] = av.z; sAT[skq * 4 + 3][sr] = av.w;
    sB[skq * 4 + 0][sr] = bv.x;  sB[skq * 4 + 1][sr] = bv.y;
    sB[skq * 4 + 2][sr] = bv.z;  sB[skq * 4 + 3][sr] = bv.w;
    __syncthreads();
    GEMM64_COMPUTE(sAT, sB, acc, ty, tx)
  }
  float sq = sqrtf(scal[m]);
  float ss = ssp[0];
  for (int u = 0; u < 4; u++)
    for (int v = 0; v < 4; v++) {
      int c = c0 + ty * 4 + u, x = x0 + tx * 4 + v;
      float sty = acc[u][v] * sq + msty[(size_t)b * C_ + c];
      size_t o = ((size_t)b * C_ + c) * N_ + x;
      out[o] = (1.0f - ss) * content[o] + ss * sty;
    }
}

// ---------------- host launch ----------------
extern "C" void kernel_launch(void* const* d_in, const int* in_sizes, int n_in,
                              void* d_out, int out_size, void* d_ws, size_t ws_size,
                              hipStream_t stream) {
  (void)in_sizes; (void)n_in; (void)out_size; (void)ws_size;
  const float* content = (const float*)d_in[0];
  const float* style   = (const float*)d_in[1];
  const float* ssp     = (const float*)d_in[2];
  float* out = (float*)d_out;
  float* W = (float*)d_ws;

  // workspace layout (floats)
  size_t off = 0;
  float* fc   = W + off; off += (size_t)B_ * C_ * N_;
  float* fs   = W + off; off += (size_t)B_ * C_ * N_;   // recon aliases fs later
  float* nsP  = W + off; off += (size_t)B_ * NP_ * C_;
  float* ncP  = W + off; off += (size_t)B_ * C_ * NP_;
  float* A4   = W + off; off += (size_t)4 * CC_;
  float* YpA  = W + off; off += (size_t)16 * CC_;
  float* YpB  = W + off; off += (size_t)16 * CC_;
  float* ZpA  = W + off; off += (size_t)16 * CC_;
  float* ZpB  = W + off; off += (size_t)16 * CC_;
  float* scal = W + off; off += 4;
  float* msty = W + off; off += (size_t)B_ * C_;
  float* mr   = W + off; off += (size_t)B_ * C_;
  float* pmr  = W + off; off += (size_t)B_ * 16 * C_;
  float* q    = W + off; off += (size_t)B_ * NP_;
  float* kni  = W + off; off += (size_t)B_ * N_;
  float* pval = W + off; off += (size_t)B_ * NCH_ * N_;
  float* Mb   = W + off; off += (size_t)NP_ * NP_;   // pcov & Tp alias Mb (dead before m_kernel)
  int* pidx = (int*)(W + off); off += (size_t)B_ * NCH_ * N_;
  int* idxb = (int*)(W + off); off += (size_t)B_ * N_;
  float* pcov = Mb;          // 9*4*CC = 2.36M floats <= 6.25M floats of Mb
  float* Tp   = Mb;          // 16*CC = 1.05M floats; used only during NS (pcov dead by then)
  float* recon = fs;         // fs dead after whiten_pad

  hipMemsetAsync(nsP, 0, (size_t)B_ * NP_ * C_ * sizeof(float), stream);
  hipMemsetAsync(ncP, 0, (size_t)B_ * C_ * NP_ * sizeof(float), stream);

  center_kernel<<<2 * B_ * C_, 256, 0, stream>>>(content, style, fc, fs, msty);
  cov_kernel<<<dim3(4, 4, 4 * KCH_), 256, 0, stream>>>(fc, fs, pcov);
  covreduce<<<4 * CC_ / 256, 256, 0, stream>>>(pcov, A4);
  ns_init<<<dim3(16, 4), 256, 0, stream>>>(A4, YpA, ZpA, scal);

  float *Ycur = YpA, *Zcur = ZpA, *Yalt = YpB, *Zalt = ZpB;
  for (int it = 0; it < NSIT_; it++) {
    ns_stepA<<<dim3(4, 4, 16), 256, 0, stream>>>(Zcur, Ycur, Tp);
    ns_stepB<<<dim3(4, 4, 32), 256, 0, stream>>>(Ycur, Zcur, Tp, Yalt, Zalt);
    float* t;
    t = Ycur; Ycur = Yalt; Yalt = t;
    t = Zcur; Zcur = Zalt; Zalt = t;
  }

  whiten_pad<<<dim3(36, 4, 4), 256, 0, stream>>>(Zcur, scal, fc, fs, ncP, nsP);
  q_kernel<<<(B_ * NP_ + 3) / 4, 256, 0, stream>>>(nsP, q);
  kninv_kernel<<<(B_ * N_ + 255) / 256, 256, 0, stream>>>(q, kni);

  for (int b = 0; b < B_; b++) {
    m_kernel<<<dim3((NP_ + 63) / 64, (NP_ + 63) / 64), 256, 0, stream>>>(
        nsP + (size_t)b * NP_ * C_, ncP + (size_t)b * C_ * NP_, Mb);
    score_kernel<<<dim3(N_ / 256, NCH_), 256, 0, stream>>>(Mb, kni, pval, pidx, b);
  }
  argmax_final<<<(B_ * N_ + 255) / 256, 256, 0, stream>>>(pval, pidx, idxb);
  reassemble_kernel<<<B_ * N_, 256, 0, stream>>>(nsP, idxb, recon);
  rmean_part<<<dim3(16, B_), 256, 0, stream>>>(recon, pmr);
  rmean_fin<<<B_, 256, 0, stream>>>(pmr, mr);
  color_blend<<<dim3(36, 4, B_), 256, 0, stream>>>(
      Ycur, scal, recon, mr, msty, content, ssp, out);
}

// Round 4
// 436.823 us; speedup vs baseline: 2.2443x; 1.0606x over previous
//
#include <hip/hip_runtime.h>

// Problem constants (setup_inputs: B=2, C=256, H=W=48, p=3)
constexpr int B_  = 2;
constexpr int C_  = 256;
constexpr int H_  = 48;
constexpr int W_  = 48;
constexpr int N_  = H_ * W_;          // 2304
constexpr int PH_ = H_ + 2;           // 50
constexpr int PW_ = W_ + 2;           // 50
constexpr int NP_ = PH_ * PW_;        // 2500
constexpr int CC_ = C_ * C_;          // 65536
constexpr int NCH_ = 36;              // n-chunks for score partial argmax
constexpr int NC_  = N_ / NCH_;       // 64
constexpr int NSIT_ = 6;              // Newton-Schulz iterations (e6 ~ 1e-18)
constexpr int KCH_ = 9;               // cov K-chunks (2304 = 9*256)

// ---------------- reduction helpers ----------------
__device__ inline float waveRed(float v) {
  #pragma unroll
  for (int o = 32; o > 0; o >>= 1) v += __shfl_down(v, o);
  return v;
}

// 16-FMA inner step on staged 64-wide tiles
#define GEMM64_COMPUTE(sAT, sB, acc, ty, tx)                        \
  _Pragma("unroll")                                                 \
  for (int kk = 0; kk < 16; kk++) {                                 \
    float4 a = *(const float4*)&sAT[kk][(ty) * 4];                  \
    float4 b = *(const float4*)&sB[kk][(tx) * 4];                   \
    acc[0][0] += a.x * b.x; acc[0][1] += a.x * b.y;                 \
    acc[0][2] += a.x * b.z; acc[0][3] += a.x * b.w;                 \
    acc[1][0] += a.y * b.x; acc[1][1] += a.y * b.y;                 \
    acc[1][2] += a.y * b.z; acc[1][3] += a.y * b.w;                 \
    acc[2][0] += a.z * b.x; acc[2][1] += a.z * b.y;                 \
    acc[2][2] += a.z * b.z; acc[2][3] += a.z * b.w;                 \
    acc[3][0] += a.w * b.x; acc[3][1] += a.w * b.y;                 \
    acc[3][2] += a.w * b.z; acc[3][3] += a.w * b.w;                 \
  }

// ---------------- kernels ----------------

// Per-(b,c) mean over N, write centered rows. which=0: content->fc, 1: style->fs
__global__ __launch_bounds__(256) void center_kernel(
    const float* __restrict__ content, const float* __restrict__ style,
    float* __restrict__ fc, float* __restrict__ fs, float* __restrict__ mean_s) {
  int t = blockIdx.x;
  int which = t / (B_ * C_);
  int bc = t % (B_ * C_);
  const float* src = which ? style : content;
  float* dst = which ? fs : fc;
  const float* row = src + (size_t)bc * N_;
  float acc = 0.f;
  for (int i = threadIdx.x; i < N_; i += 256) acc += row[i];
  __shared__ float sm[4];
  float r = waveRed(acc);
  if ((threadIdx.x & 63) == 0) sm[threadIdx.x >> 6] = r;
  __syncthreads();
  float mean = (sm[0] + sm[1] + sm[2] + sm[3]) * (1.0f / N_);
  for (int i = threadIdx.x; i < N_; i += 256) dst[(size_t)bc * N_ + i] = row[i] - mean;
  if (which == 1 && threadIdx.x == 0) mean_s[bc] = mean;
}

// K-split covariance partials: z = ci*4+m. 64x64 tile, both operands transposed-staged.
__global__ __launch_bounds__(256) void cov_kernel(
    const float* __restrict__ fc, const float* __restrict__ fs, float* __restrict__ pcov) {
  int z = blockIdx.z;
  int m = z & 3, ci = z >> 2;
  const float* f = (m < 2) ? (fc + (size_t)m * C_ * N_) : (fs + (size_t)(m - 2) * C_ * N_);
  int i0 = blockIdx.y * 64, j0 = blockIdx.x * 64;
  int t = threadIdx.x;
  int tx = t & 15, ty = t >> 4;
  int sr = t >> 2, skq = t & 3;
  __shared__ float sAT[16][68], sB[16][68];
  float acc[4][4] = {};
  int k0e = ci * 256 + 256;
  for (int k0 = ci * 256; k0 < k0e; k0 += 16) {
    float4 av = *(const float4*)&f[(size_t)(i0 + sr) * N_ + k0 + skq * 4];
    float4 bv = *(const float4*)&f[(size_t)(j0 + sr) * N_ + k0 + skq * 4];
    __syncthreads();
    sAT[skq * 4 + 0][sr] = av.x; sAT[skq * 4 + 1][sr] = av.y;
    sAT[skq * 4 + 2][sr] = av.z; sAT[skq * 4 + 3][sr] = av.w;
    sB[skq * 4 + 0][sr] = bv.x;  sB[skq * 4 + 1][sr] = bv.y;
    sB[skq * 4 + 2][sr] = bv.z;  sB[skq * 4 + 3][sr] = bv.w;
    __syncthreads();
    GEMM64_COMPUTE(sAT, sB, acc, ty, tx)
  }
  float* out = pcov + ((size_t)ci * 4 + m) * CC_;
  for (int u = 0; u < 4; u++)
    for (int v = 0; v < 4; v++)
      out[(size_t)(i0 + ty * 4 + u) * C_ + (j0 + tx * 4 + v)] = acc[u][v];
}

// A4[m] = (sum_ci pcov[ci][m]) / (N-1)
__global__ __launch_bounds__(256) void covreduce(
    const float* __restrict__ pcov, float* __restrict__ A4) {
  int t = blockIdx.x * 256 + threadIdx.x;
  float acc = 0.f;
  #pragma unroll
  for (int ci = 0; ci < KCH_; ci++) acc += pcov[(size_t)ci * 4 * CC_ + t];
  A4[t] = acc * (1.0f / (float)(N_ - 1));
}

// Y = A/s, Z = I (consolidated). grid (16,4): by=m, bx=slice
__global__ __launch_bounds__(256) void ns_init(
    const float* __restrict__ A4, float* __restrict__ Y, float* __restrict__ Z,
    float* __restrict__ scal) {
  int m = blockIdx.y, s = blockIdx.x;
  const float* A = A4 + (size_t)m * CC_;
  float d = A[(size_t)threadIdx.x * 257];
  __shared__ float sm[4];
  float r = waveRed(d);
  if ((threadIdx.x & 63) == 0) sm[threadIdx.x >> 6] = r;
  __syncthreads();
  float trace = sm[0] + sm[1] + sm[2] + sm[3];
  float sc = 1.1f * trace / (float)C_;
  if (s == 0 && threadIdx.x == 0) scal[m] = sc;
  float inv = 1.0f / sc;
  int i0 = s * (CC_ / 16);
  for (int i = i0 + threadIdx.x; i < i0 + CC_ / 16; i += 256) {
    Y[(size_t)m * CC_ + i] = A[i] * inv;
    Z[(size_t)m * CC_ + i] = ((i >> 8) == (i & 255)) ? 1.0f : 0.0f;
  }
}

// T = 3I - Z*Y. 32x32 tiles, BK=32. grid (8,8,4): z=m
__global__ __launch_bounds__(256) void ns_stepA(
    const float* __restrict__ Z, const float* __restrict__ Y, float* __restrict__ T) {
  int m = blockIdx.z;
  const float* A = Z + (size_t)m * CC_;
  const float* Bm = Y + (size_t)m * CC_;
  float* out = T + (size_t)m * CC_;
  int i0 = blockIdx.y * 32, j0 = blockIdx.x * 32;
  int t = threadIdx.x;
  int tx = t & 15, ty = t >> 4;
  int sr = t >> 3, sc4 = t & 7;      // staging: row/k-row sr (0..31), quad sc4
  __shared__ float sAT[32][36], sB[32][36];
  float acc[2][2] = {};
  for (int k0 = 0; k0 < 256; k0 += 32) {
    float4 av = *(const float4*)&A[(size_t)(i0 + sr) * 256 + k0 + sc4 * 4];
    float4 bv = *(const float4*)&Bm[(size_t)(k0 + sr) * 256 + j0 + sc4 * 4];
    __syncthreads();
    sAT[sc4 * 4 + 0][sr] = av.x; sAT[sc4 * 4 + 1][sr] = av.y;
    sAT[sc4 * 4 + 2][sr] = av.z; sAT[sc4 * 4 + 3][sr] = av.w;
    *(float4*)&sB[sr][sc4 * 4] = bv;
    __syncthreads();
    #pragma unroll
    for (int kk = 0; kk < 32; kk++) {
      float2 a = *(const float2*)&sAT[kk][ty * 2];
      float2 b = *(const float2*)&sB[kk][tx * 2];
      acc[0][0] += a.x * b.x; acc[0][1] += a.x * b.y;
      acc[1][0] += a.y * b.x; acc[1][1] += a.y * b.y;
    }
    __syncthreads();
  }
  for (int u = 0; u < 2; u++)
    for (int v = 0; v < 2; v++) {
      int i = i0 + ty * 2 + u, j = j0 + tx * 2 + v;
      float d = (i == j) ? 3.0f : 0.0f;
      out[(size_t)i * 256 + j] = d - acc[u][v];
    }
}

// grid (8,8,8): m=z&3, doY=z<4. Yn = 0.5*Y*T ; Zn = 0.5*T*Z
__global__ __launch_bounds__(256) void ns_stepB(
    const float* __restrict__ Y, const float* __restrict__ Z, const float* __restrict__ T,
    float* __restrict__ Yn, float* __restrict__ Zn) {
  int z = blockIdx.z;
  int m = z & 3;
  bool doY = (z < 4);
  const float* A = (doY ? Y : T) + (size_t)m * CC_;
  const float* Bm = (doY ? T : Z) + (size_t)m * CC_;
  float* out = (doY ? Yn : Zn) + (size_t)m * CC_;
  int i0 = blockIdx.y * 32, j0 = blockIdx.x * 32;
  int t = threadIdx.x;
  int tx = t & 15, ty = t >> 4;
  int sr = t >> 3, sc4 = t & 7;
  __shared__ float sAT[32][36], sB[32][36];
  float acc[2][2] = {};
  for (int k0 = 0; k0 < 256; k0 += 32) {
    float4 av = *(const float4*)&A[(size_t)(i0 + sr) * 256 + k0 + sc4 * 4];
    float4 bv = *(const float4*)&Bm[(size_t)(k0 + sr) * 256 + j0 + sc4 * 4];
    __syncthreads();
    sAT[sc4 * 4 + 0][sr] = av.x; sAT[sc4 * 4 + 1][sr] = av.y;
    sAT[sc4 * 4 + 2][sr] = av.z; sAT[sc4 * 4 + 3][sr] = av.w;
    *(float4*)&sB[sr][sc4 * 4] = bv;
    __syncthreads();
    #pragma unroll
    for (int kk = 0; kk < 32; kk++) {
      float2 a = *(const float2*)&sAT[kk][ty * 2];
      float2 b = *(const float2*)&sB[kk][tx * 2];
      acc[0][0] += a.x * b.x; acc[0][1] += a.x * b.y;
      acc[1][0] += a.y * b.x; acc[1][1] += a.y * b.y;
    }
    __syncthreads();
  }
  for (int u = 0; u < 2; u++)
    for (int v = 0; v < 2; v++) {
      int i = i0 + ty * 2 + u, j = j0 + tx * 2 + v;
      out[(size_t)i * 256 + j] = 0.5f * acc[u][v];
    }
}

// Z/sqrt(s) * f -> padded buffers. m<2: content -> ncP [b][c][NP]; m>=2: style -> nsP [b][NP][c]
// grid (36,4,4)
__global__ __launch_bounds__(256) void whiten_pad(
    const float* __restrict__ Zf, const float* __restrict__ scal,
    const float* __restrict__ fc, const float* __restrict__ fs,
    float* __restrict__ ncP, float* __restrict__ nsP) {
  int m = blockIdx.z;
  const float* f = (m < 2) ? (fc + (size_t)m * C_ * N_) : (fs + (size_t)(m - 2) * C_ * N_);
  int c0 = blockIdx.y * 64, x0 = blockIdx.x * 64;
  int t = threadIdx.x;
  int tx = t & 15, ty = t >> 4;
  int sr = t >> 2, skq = t & 3;
  int bkk = t & 15, bc4 = t >> 4;
  __shared__ float sAT[16][68], sB[16][68];
  float acc[4][4] = {};
  for (int k0 = 0; k0 < 256; k0 += 16) {
    float4 av = *(const float4*)&Zf[(size_t)m * CC_ + (size_t)(c0 + sr) * 256 + k0 + skq * 4];
    float4 bv = *(const float4*)&f[(size_t)(k0 + bkk) * N_ + x0 + bc4 * 4];
    __syncthreads();
    sAT[skq * 4 + 0][sr] = av.x; sAT[skq * 4 + 1][sr] = av.y;
    sAT[skq * 4 + 2][sr] = av.z; sAT[skq * 4 + 3][sr] = av.w;
    *(float4*)&sB[bkk][bc4 * 4] = bv;
    __syncthreads();
    GEMM64_COMPUTE(sAT, sB, acc, ty, tx)
  }
  float rs = rsqrtf(scal[m]);
  int b = (m < 2) ? m : (m - 2);
  for (int u = 0; u < 4; u++)
    for (int v = 0; v < 4; v++) {
      int c = c0 + ty * 4 + u, x = x0 + tx * 4 + v;
      int h = x / W_, w = x % W_;
      int pp = (h + 1) * PW_ + (w + 1);
      float val = acc[u][v] * rs;
      if (m < 2) ncP[((size_t)b * C_ + c) * NP_ + pp] = val;
      else       nsP[((size_t)b * NP_ + pp) * C_ + c] = val;
    }
}

// q[b][p] = sum_c nsP[b][p][c]^2
__global__ __launch_bounds__(256) void q_kernel(const float* __restrict__ nsP, float* __restrict__ q) {
  int wid = (blockIdx.x * 256 + threadIdx.x) >> 6;
  int lane = threadIdx.x & 63;
  if (wid >= B_ * NP_) return;
  const float* v = nsP + (size_t)wid * C_;
  float acc = 0.f;
  #pragma unroll
  for (int c = lane; c < C_; c += 64) { float t = v[c]; acc += t * t; }
  acc = waveRed(acc);
  if (lane == 0) q[wid] = acc;
}

// kninv[b][n] = rsqrt( sum over 3x3 of q )
__global__ __launch_bounds__(256) void kninv_kernel(const float* __restrict__ q, float* __restrict__ kninv) {
  int t = blockIdx.x * 256 + threadIdx.x;
  if (t >= B_ * N_) return;
  int b = t / N_, n = t % N_;
  int hn = n / W_, wn = n % W_;
  const float* qb = q + (size_t)b * NP_ + hn * PW_ + wn;
  float s = 0.f;
  #pragma unroll
  for (int i = 0; i < 3; i++)
    #pragma unroll
    for (int j = 0; j < 3; j++) s += qb[i * PW_ + j];
  kninv[t] = rsqrtf(s);
}

// M = nsP[b] (2500x256) * ncP[b] (256x2500). 128x64 tiles, grid (40,20).
__global__ __launch_bounds__(256) void m_kernel(
    const float* __restrict__ Asty, const float* __restrict__ Bcon, float* __restrict__ M) {
  int i0 = blockIdx.y * 128, j0 = blockIdx.x * 64;
  int t = threadIdx.x;
  int tx = t & 15, ty = t >> 4;
  int sr = t >> 1, half = t & 1;     // A-staging: row sr (0..127), k-half
  int bkk = t >> 4, bc4 = t & 15;    // B-staging
  __shared__ float sAT[16][132], sB[16][68];
  float acc[8][4] = {};
  bool arow_ok = (i0 + sr) < NP_;
  int bcol = j0 + bc4 * 4;
  bool bcol_ok4 = (bcol + 3) < NP_;
  for (int k0 = 0; k0 < 256; k0 += 16) {
    float4 a0 = {0,0,0,0}, a1 = {0,0,0,0}, bv = {0,0,0,0};
    if (arow_ok) {
      a0 = *(const float4*)&Asty[(size_t)(i0 + sr) * C_ + k0 + half * 8];
      a1 = *(const float4*)&Asty[(size_t)(i0 + sr) * C_ + k0 + half * 8 + 4];
    }
    if (bcol_ok4) bv = *(const float4*)&Bcon[(size_t)(k0 + bkk) * NP_ + bcol];
    else {
      float tmp[4] = {0,0,0,0};
      for (int j = 0; j < 4; j++) if (bcol + j < NP_) tmp[j] = Bcon[(size_t)(k0 + bkk) * NP_ + bcol + j];
      bv.x = tmp[0]; bv.y = tmp[1]; bv.z = tmp[2]; bv.w = tmp[3];
    }
    __syncthreads();
    sAT[half * 8 + 0][sr] = a0.x; sAT[half * 8 + 1][sr] = a0.y;
    sAT[half * 8 + 2][sr] = a0.z; sAT[half * 8 + 3][sr] = a0.w;
    sAT[half * 8 + 4][sr] = a1.x; sAT[half * 8 + 5][sr] = a1.y;
    sAT[half * 8 + 6][sr] = a1.z; sAT[half * 8 + 7][sr] = a1.w;
    *(float4*)&sB[bkk][bc4 * 4] = bv;
    __syncthreads();
    #pragma unroll
    for (int kk = 0; kk < 16; kk++) {
      float4 aa0 = *(const float4*)&sAT[kk][ty * 8];
      float4 aa1 = *(const float4*)&sAT[kk][ty * 8 + 4];
      float4 b = *(const float4*)&sB[kk][tx * 4];
      float ar[8] = {aa0.x, aa0.y, aa0.z, aa0.w, aa1.x, aa1.y, aa1.z, aa1.w};
      #pragma unroll
      for (int u = 0; u < 8; u++) {
        acc[u][0] += ar[u] * b.x; acc[u][1] += ar[u] * b.y;
        acc[u][2] += ar[u] * b.z; acc[u][3] += ar[u] * b.w;
      }
    }
    __syncthreads();
  }
  for (int u = 0; u < 8; u++) {
    int i = i0 + ty * 8 + u;
    if (i >= NP_) break;
    for (int v = 0; v < 4; v++) {
      int j = j0 + tx * 4 + v;
      if (j < NP_) M[(size_t)i * NP_ + j] = acc[u][v];
    }
  }
}

// Partial argmax over an n-chunk for each content position m.
__global__ __launch_bounds__(256) void score_kernel(
    const float* __restrict__ M, const float* __restrict__ kninv,
    float* __restrict__ pval, int* __restrict__ pidx, int b) {
  int m = blockIdx.x * 256 + threadIdx.x;
  int h = m / W_, w = m % W_;
  int cm = h * PW_ + w;
  int n0 = blockIdx.y * NC_;
  const float* kni = kninv + (size_t)b * N_;
  float best = -3.4e38f;
  int bidx = n0;
  for (int n = n0; n < n0 + NC_; n++) {
    int hn = n / W_, wn = n % W_;
    int rn = hn * PW_ + wn;
    const float* base = M + (size_t)rn * NP_ + cm;
    float s = 0.f;
    #pragma unroll
    for (int i = 0; i < 3; i++)
      #pragma unroll
      for (int j = 0; j < 3; j++) s += base[(size_t)(i * PW_ + j) * (NP_ + 1)];
    s *= kni[n];
    if (s > best) { best = s; bidx = n; }
  }
  pval[((size_t)b * NCH_ + blockIdx.y) * N_ + m] = best;
  pidx[((size_t)b * NCH_ + blockIdx.y) * N_ + m] = bidx;
}

// Final argmax across chunks (ascending => first-max wins, matches jnp.argmax)
__global__ __launch_bounds__(256) void argmax_final(
    const float* __restrict__ pval, const int* __restrict__ pidx, int* __restrict__ idxb) {
  int t = blockIdx.x * 256 + threadIdx.x;
  if (t >= B_ * N_) return;
  int b = t / N_, m = t % N_;
  float best = -3.4e38f; int bidx = 0;
  for (int ch = 0; ch < NCH_; ch++) {
    float v = pval[((size_t)b * NCH_ + ch) * N_ + m];
    int i = pidx[((size_t)b * NCH_ + ch) * N_ + m];
    if (v > best) { best = v; bidx = i; }
  }
  idxb[t] = bidx;
}

// Overlap-add reassembly: recon[b][m][c] (position-major)
__global__ __launch_bounds__(256) void reassemble_kernel(
    const float* __restrict__ nsP, const int* __restrict__ idxb, float* __restrict__ recon) {
  int bm = blockIdx.x;
  int b = bm / N_, m = bm % N_;
  int h = m / W_, w = m % W_;
  int c = threadIdx.x;
  float acc = 0.f; int cnt = 0;
  for (int di = 0; di < 3; di++) {
    int hs = h + 1 - di; if (hs < 0 || hs >= H_) continue;
    for (int dj = 0; dj < 3; dj++) {
      int ws = w + 1 - dj; if (ws < 0 || ws >= W_) continue;
      int n = idxb[(size_t)b * N_ + hs * W_ + ws];
      int hn = n / W_, wn = n % W_;
      int pp = (hn + di) * PW_ + (wn + dj);
      acc += nsP[((size_t)b * NP_ + pp) * C_ + c];
      cnt++;
    }
  }
  recon[((size_t)b * N_ + m) * C_ + c] = acc / (float)cnt;
}

// Partial column sums of recon over x-chunks
__global__ __launch_bounds__(256) void rmean_part(const float* __restrict__ recon, float* __restrict__ pmr) {
  int b = blockIdx.y, ch = blockIdx.x, c = threadIdx.x;
  float acc = 0.f;
  int x0 = ch * (N_ / 16);
  for (int x = x0; x < x0 + (N_ / 16); x++) acc += recon[((size_t)b * N_ + x) * C_ + c];
  pmr[((size_t)b * 16 + ch) * C_ + c] = acc;
}

__global__ __launch_bounds__(256) void rmean_fin(const float* __restrict__ pmr, float* __restrict__ mr) {
  int b = blockIdx.x, c = threadIdx.x;
  float acc = 0.f;
  for (int ch = 0; ch < 16; ch++) acc += pmr[((size_t)b * 16 + ch) * C_ + c];
  mr[(size_t)b * C_ + c] = acc * (1.0f / N_);
}

// stylized = sqrt(cov_s)*(recon-mr) + mean_s ; out = (1-ss)*content + ss*stylized
// grid (36,4,2)
__global__ __launch_bounds__(256) void color_blend(
    const float* __restrict__ Yf, const float* __restrict__ scal,
    const float* __restrict__ recon, const float* __restrict__ mr,
    const float* __restrict__ msty, const float* __restrict__ content,
    const float* __restrict__ ssp, float* __restrict__ out) {
  int b = blockIdx.z;
  int m = 2 + b;
  int c0 = blockIdx.y * 64, x0 = blockIdx.x * 64;
  int t = threadIdx.x;
  int tx = t & 15, ty = t >> 4;
  int sr = t >> 2, skq = t & 3;
  __shared__ float sAT[16][68], sB[16][68];
  float acc[4][4] = {};
  for (int k0 = 0; k0 < 256; k0 += 16) {
    float4 av = *(const float4*)&Yf[(size_t)m * CC_ + (size_t)(c0 + sr) * 256 + k0 + skq * 4];
    float4 bm4 = *(const float4*)&mr[(size_t)b * C_ + k0 + skq * 4];
    float4 bv = *(const float4*)&recon[((size_t)b * N_ + x0 + sr) * C_ + k0 + skq * 4];
    bv.x -= bm4.x; bv.y -= bm4.y; bv.z -= bm4.z; bv.w -= bm4.w;
    __syncthreads();
    sAT[skq * 4 + 0][sr] = av.x; sAT[skq * 4 + 1][sr] = av.y;
    sAT[skq * 4 + 2][sr] = av.z; sAT[skq * 4 + 3][sr] = av.w;
    sB[skq * 4 + 0][sr] = bv.x;  sB[skq * 4 + 1][sr] = bv.y;
    sB[skq * 4 + 2][sr] = bv.z;  sB[skq * 4 + 3][sr] = bv.w;
    __syncthreads();
    GEMM64_COMPUTE(sAT, sB, acc, ty, tx)
  }
  float sq = sqrtf(scal[m]);
  float ss = ssp[0];
  for (int u = 0; u < 4; u++)
    for (int v = 0; v < 4; v++) {
      int c = c0 + ty * 4 + u, x = x0 + tx * 4 + v;
      float sty = acc[u][v] * sq + msty[(size_t)b * C_ + c];
      size_t o = ((size_t)b * C_ + c) * N_ + x;
      out[o] = (1.0f - ss) * content[o] + ss * sty;
    }
}

// ---------------- host launch ----------------
extern "C" void kernel_launch(void* const* d_in, const int* in_sizes, int n_in,
                              void* d_out, int out_size, void* d_ws, size_t ws_size,
                              hipStream_t stream) {
  (void)in_sizes; (void)n_in; (void)out_size; (void)ws_size;
  const float* content = (const float*)d_in[0];
  const float* style   = (const float*)d_in[1];
  const float* ssp     = (const float*)d_in[2];
  float* out = (float*)d_out;
  float* W = (float*)d_ws;

  // workspace layout (floats)
  size_t off = 0;
  float* fc   = W + off; off += (size_t)B_ * C_ * N_;
  float* fs   = W + off; off += (size_t)B_ * C_ * N_;   // recon aliases fs later
  float* nsP  = W + off; off += (size_t)B_ * NP_ * C_;
  float* ncP  = W + off; off += (size_t)B_ * C_ * NP_;
  float* A4   = W + off; off += (size_t)4 * CC_;
  float* Ya   = W + off; off += (size_t)4 * CC_;
  float* Yb   = W + off; off += (size_t)4 * CC_;
  float* Za   = W + off; off += (size_t)4 * CC_;
  float* Zb   = W + off; off += (size_t)4 * CC_;
  float* scal = W + off; off += 4;
  float* msty = W + off; off += (size_t)B_ * C_;
  float* mr   = W + off; off += (size_t)B_ * C_;
  float* pmr  = W + off; off += (size_t)B_ * 16 * C_;
  float* q    = W + off; off += (size_t)B_ * NP_;
  float* kni  = W + off; off += (size_t)B_ * N_;
  float* pval = W + off; off += (size_t)B_ * NCH_ * N_;
  float* Mb   = W + off; off += (size_t)NP_ * NP_;   // pcov & T alias Mb (dead before m_kernel)
  int* pidx = (int*)(W + off); off += (size_t)B_ * NCH_ * N_;
  int* idxb = (int*)(W + off); off += (size_t)B_ * N_;
  float* pcov = Mb;          // 9*4*CC = 2.36M floats <= 6.25M floats of Mb
  float* T    = Mb;          // 4*CC floats; used only during NS (pcov dead by then)
  float* recon = fs;         // fs dead after whiten_pad

  hipMemsetAsync(nsP, 0, (size_t)B_ * NP_ * C_ * sizeof(float), stream);
  hipMemsetAsync(ncP, 0, (size_t)B_ * C_ * NP_ * sizeof(float), stream);

  center_kernel<<<2 * B_ * C_, 256, 0, stream>>>(content, style, fc, fs, msty);
  cov_kernel<<<dim3(4, 4, 4 * KCH_), 256, 0, stream>>>(fc, fs, pcov);
  covreduce<<<4 * CC_ / 256, 256, 0, stream>>>(pcov, A4);
  ns_init<<<dim3(16, 4), 256, 0, stream>>>(A4, Ya, Za, scal);

  float *Ycur = Ya, *Zcur = Za, *Yalt = Yb, *Zalt = Zb;
  for (int it = 0; it < NSIT_; it++) {
    ns_stepA<<<dim3(8, 8, 4), 256, 0, stream>>>(Zcur, Ycur, T);
    ns_stepB<<<dim3(8, 8, 8), 256, 0, stream>>>(Ycur, Zcur, T, Yalt, Zalt);
    float* tp;
    tp = Ycur; Ycur = Yalt; Yalt = tp;
    tp = Zcur; Zcur = Zalt; Zalt = tp;
  }

  whiten_pad<<<dim3(36, 4, 4), 256, 0, stream>>>(Zcur, scal, fc, fs, ncP, nsP);
  q_kernel<<<(B_ * NP_ + 3) / 4, 256, 0, stream>>>(nsP, q);
  kninv_kernel<<<(B_ * N_ + 255) / 256, 256, 0, stream>>>(q, kni);

  for (int b = 0; b < B_; b++) {
    m_kernel<<<dim3(40, 20), 256, 0, stream>>>(
        nsP + (size_t)b * NP_ * C_, ncP + (size_t)b * C_ * NP_, Mb);
    score_kernel<<<dim3(N_ / 256, NCH_), 256, 0, stream>>>(Mb, kni, pval, pidx, b);
  }
  argmax_final<<<(B_ * N_ + 255) / 256, 256, 0, stream>>>(pval, pidx, idxb);
  reassemble_kernel<<<B_ * N_, 256, 0, stream>>>(nsP, idxb, recon);
  rmean_part<<<dim3(16, B_), 256, 0, stream>>>(recon, pmr);
  rmean_fin<<<B_, 256, 0, stream>>>(pmr, mr);
  color_blend<<<dim3(36, 4, B_), 256, 0, stream>>>(
      Ycur, scal, recon, mr, msty, content, ssp, out);
}